// Round 8
// baseline (518.980 us; speedup 1.0000x reference)
//
#include <hip/hip_runtime.h>
#include <hip/hip_bf16.h>

namespace {

constexpr int Bb = 8;
constexpr int Nn = 2048;
constexpr int Hh = 128;
constexpr int Kp = 1434;
constexpr int KpPad = 1536;
constexpr float kEps = 1e-10f;
constexpr float kBig = 1e10f;

using bf16x8 = __attribute__((ext_vector_type(8))) short;
using f32x4  = __attribute__((ext_vector_type(4))) float;
using f32x16 = __attribute__((ext_vector_type(16))) float;

__device__ __forceinline__ float bf2f(unsigned u) {
  union { float f; unsigned q; } x; x.q = u << 16; return x.f;
}

__device__ __forceinline__ unsigned short f2bfbits(float f) {
  __hip_bfloat16 h = __float2bfloat16(f);
  return *reinterpret_cast<unsigned short*>(&h);
}

template<typename TA>
__device__ __forceinline__ void load8(const TA* p, float v[8]) {
  const float4* q = reinterpret_cast<const float4*>(p);
  float4 x0 = q[0], x1 = q[1];
  v[0]=x0.x; v[1]=x0.y; v[2]=x0.z; v[3]=x0.w;
  v[4]=x1.x; v[5]=x1.y; v[6]=x1.z; v[7]=x1.w;
}

template<typename TC>
__device__ __forceinline__ TC cvt_out(float v) {
  if constexpr (sizeof(TC) == 2) {
    return __float2bfloat16(v);
  } else {
    return v;
  }
}

__device__ __forceinline__ void gload_lds16(const void* g, void* l) {
  __builtin_amdgcn_global_load_lds(
      (const __attribute__((address_space(1))) void*)g,
      (__attribute__((address_space(3))) void*)l, 16, 0, 0);
}

// ---------------- bf16 MFMA GEMM: C = A(row-gathered) @ Bt(row-gathered)^T ---------------
// round 8: 32x32x16 MFMA (half the MFMA instructions, same LDS traffic).
// C/D mapping (m74/m101): col = lane&31, row = (reg&3) + 8*(reg>>2) + 4*(lane>>5).
template<typename TC>
__global__ __launch_bounds__(256, 4)
void mgemm_k(const __hip_bfloat16* __restrict__ A, long lda, long sA,
             const __hip_bfloat16* __restrict__ Bt, long ldb, long sB,
             const int* __restrict__ ag, int ag_stride, int Mg,
             const int* __restrict__ bg, int bg_stride, int Ng,
             TC* __restrict__ C, long ldc, long sC,
             int Ms, int Ns, int Kd)
{
  __shared__ char smem[32768];
  char* smA = smem;
  char* smB = smem + 16384;
  const int t = threadIdx.x;

  // XCD-chunked bijective swizzle (nwg % 8 == 0 at all call sites)
  const int gx = gridDim.x, gy = gridDim.y;
  const int nwg = gx * gy * (int)gridDim.z;
  int lin = ((int)blockIdx.z * gy + (int)blockIdx.y) * gx + (int)blockIdx.x;
  lin = (lin & 7) * (nwg >> 3) + (lin >> 3);
  const int bx = lin % gx;
  const int by = (lin / gx) % gy;
  const int b  = lin / (gx * gy);

  const int m0 = by * 128, n0 = bx * 128;
  const int lane = t & 63, w = t >> 6;
  const int wr = w >> 1, wc = w & 1;

  const __hip_bfloat16* Ab = A + (size_t)b * sA;
  const __hip_bfloat16* Bb_ = Bt + (size_t)b * sB;

  const int srow = t >> 3;
  const int scol = ((t & 7) ^ (srow & 7)) * 16;
  const char* gA[4]; const char* gB[4];
#pragma unroll
  for (int q = 0; q < 4; ++q) {
    const int rowq = q * 32 + srow;
    long ga = m0 + rowq;
    if (ag) ga = (ga < Mg) ? (long)ag[(size_t)b * ag_stride + ga] : 0;
    gA[q] = (const char*)(Ab + ga * lda) + scol;
    long gb = n0 + rowq;
    if (bg) gb = (gb < Ng) ? (long)bg[(size_t)b * bg_stride + gb] : 0;
    gB[q] = (const char*)(Bb_ + gb * ldb) + scol;
  }

  f32x16 acc[2][2] = {};
  const int l31 = lane & 31, kh = lane >> 5, fx = lane & 7;

  for (int kk = 0; kk < Kd; kk += 64) {
    __syncthreads();
#pragma unroll
    for (int q = 0; q < 4; ++q) {
      gload_lds16(gA[q] + (size_t)kk * 2, smA + q * 4096 + t * 16);
      gload_lds16(gB[q] + (size_t)kk * 2, smB + q * 4096 + t * 16);
    }
    __syncthreads();
#pragma unroll
    for (int ks2 = 0; ks2 < 4; ++ks2) {
      const int slotk = ks2 * 2 + kh;
      bf16x8 aF[2], bF[2];
#pragma unroll
      for (int mi = 0; mi < 2; ++mi) {
        const int row = wr * 64 + mi * 32 + l31;
        aF[mi] = *(const bf16x8*)(smA + row * 128 + ((slotk ^ fx) << 4));
      }
#pragma unroll
      for (int ni = 0; ni < 2; ++ni) {
        const int row = wc * 64 + ni * 32 + l31;
        bF[ni] = *(const bf16x8*)(smB + row * 128 + ((slotk ^ fx) << 4));
      }
#pragma unroll
      for (int mi = 0; mi < 2; ++mi)
#pragma unroll
        for (int ni = 0; ni < 2; ++ni)
          acc[mi][ni] = __builtin_amdgcn_mfma_f32_32x32x16_bf16(
              aF[mi], bF[ni], acc[mi][ni], 0, 0, 0);
    }
  }

#pragma unroll
  for (int mi = 0; mi < 2; ++mi) {
#pragma unroll
    for (int ni = 0; ni < 2; ++ni) {
      const int col = n0 + wc * 64 + ni * 32 + l31;
      if (col >= Ns) continue;
#pragma unroll
      for (int r = 0; r < 16; ++r) {
        const int row = m0 + wr * 64 + mi * 32 + (r & 3) + 8 * (r >> 2) + 4 * kh;
        if (row >= Ms) continue;
        C[(size_t)b * sC + (size_t)row * ldc + col] = cvt_out<TC>(acc[mi][ni][r]);
      }
    }
  }
}

// ---------------- pure-bf16 layer MFMA: P[sk] = A(rows,maybe gathered) @ (Bhi+Blo)^T ------
// round 8: 32x32x16 MFMA, split-K = 4.
template<bool GATHER>
__global__ __launch_bounds__(256, 3)
void mlayer2_k(const __hip_bfloat16* __restrict__ A, long lda, long sA,
               const __hip_bfloat16* __restrict__ Bhi,
               const __hip_bfloat16* __restrict__ Blo, long ldb, long sB,
               const int* __restrict__ ag, int ag_stride, int Mg,
               float* __restrict__ P, int Mpad, int Kchunk)
{
  __shared__ char smem[49152];
  char* smA   = smem;
  char* smBhi = smem + 16384;
  char* smBlo = smem + 32768;
  const int t = threadIdx.x;
  const int b = blockIdx.z;
  const int sk = blockIdx.x;
  const int m0 = blockIdx.y * 128;
  const int k0 = sk * Kchunk;
  const int lane = t & 63, w = t >> 6;
  const int wr = w >> 1, wc = w & 1;

  const int srow = t >> 3;
  const int scol = ((t & 7) ^ (srow & 7)) * 16;
  const char* gA[4]; const char* gBhi[4]; const char* gBlo[4];
#pragma unroll
  for (int q = 0; q < 4; ++q) {
    const int rowq = q * 32 + srow;
    long ga = m0 + rowq;
    if (GATHER) ga = (ga < Mg) ? (long)ag[(size_t)b * ag_stride + ga] : 0;
    gA[q]   = (const char*)(A + (size_t)b * sA + ga * lda + k0) + scol;
    gBhi[q] = (const char*)(Bhi + (size_t)b * sB + (size_t)rowq * ldb + k0) + scol;
    gBlo[q] = (const char*)(Blo + (size_t)b * sB + (size_t)rowq * ldb + k0) + scol;
  }

  f32x16 acc[2][2] = {};
  const int l31 = lane & 31, kh = lane >> 5, fx = lane & 7;

  for (int ks = 0; ks < Kchunk; ks += 64) {
    __syncthreads();
#pragma unroll
    for (int q = 0; q < 4; ++q) {
      gload_lds16(gA[q]   + (size_t)ks * 2, smA   + q * 4096 + t * 16);
      gload_lds16(gBhi[q] + (size_t)ks * 2, smBhi + q * 4096 + t * 16);
      gload_lds16(gBlo[q] + (size_t)ks * 2, smBlo + q * 4096 + t * 16);
    }
    __syncthreads();
#pragma unroll
    for (int ks2 = 0; ks2 < 4; ++ks2) {
      const int slotk = ks2 * 2 + kh;
      bf16x8 aF[2];
#pragma unroll
      for (int mi = 0; mi < 2; ++mi) {
        const int row = wr * 64 + mi * 32 + l31;
        aF[mi] = *(const bf16x8*)(smA + row * 128 + ((slotk ^ fx) << 4));
      }
#pragma unroll
      for (int ni = 0; ni < 2; ++ni) {
        const int row = wc * 64 + ni * 32 + l31;
        const bf16x8 bhi = *(const bf16x8*)(smBhi + row * 128 + ((slotk ^ fx) << 4));
        const bf16x8 blo = *(const bf16x8*)(smBlo + row * 128 + ((slotk ^ fx) << 4));
#pragma unroll
        for (int mi = 0; mi < 2; ++mi) {
          acc[mi][ni] = __builtin_amdgcn_mfma_f32_32x32x16_bf16(aF[mi], bhi, acc[mi][ni], 0, 0, 0);
          acc[mi][ni] = __builtin_amdgcn_mfma_f32_32x32x16_bf16(aF[mi], blo, acc[mi][ni], 0, 0, 0);
        }
      }
    }
  }

  float* Pp = P + ((size_t)sk * Bb + b) * Mpad * 128;
#pragma unroll
  for (int mi = 0; mi < 2; ++mi) {
#pragma unroll
    for (int ni = 0; ni < 2; ++ni) {
      const int col = wc * 64 + ni * 32 + l31;
#pragma unroll
      for (int r = 0; r < 16; ++r) {
        const int row = m0 + wr * 64 + mi * 32 + (r & 3) + 8 * (r >> 2) + 4 * kh;
        Pp[(size_t)row * 128 + col] = acc[mi][ni][r];
      }
    }
  }
}

// ---------------- split-K reduce (sk = 4) ----------------
template<bool MASKED>
__global__ __launch_bounds__(256)
void red_layer_k(const float* __restrict__ P, const float* __restrict__ bias,
                 const float* __restrict__ mask, float* __restrict__ out)
{
  const size_t o = ((size_t)blockIdx.x * 256 + threadIdx.x) * 4;
  const size_t stride = (size_t)Bb * Nn * Hh;
  float4 s = {0.f, 0.f, 0.f, 0.f};
#pragma unroll
  for (int sk = 0; sk < 4; ++sk) {
    const float4 v = *(const float4*)(P + sk * stride + o);
    s.x += v.x; s.y += v.y; s.z += v.z; s.w += v.w;
  }
  const int h = (int)(o & 127);
  const float4 bi = *(const float4*)(bias + h);
  s.x = fmaxf(s.x + bi.x, 0.f);
  s.y = fmaxf(s.y + bi.y, 0.f);
  s.z = fmaxf(s.z + bi.z, 0.f);
  s.w = fmaxf(s.w + bi.w, 0.f);
  if (MASKED) {
    const int n = (int)((o >> 7) & (Nn - 1));
    const int b = (int)(o >> 18);
    const float m = mask[b * Nn + n];
    s.x *= m; s.y *= m; s.z *= m; s.w *= m;
  }
  *(float4*)(out + o) = s;
}

__global__ __launch_bounds__(128)
void red_hout_k(const float* __restrict__ P, float* __restrict__ Hout)
{
  const int k = blockIdx.x, b = blockIdx.y, h = threadIdx.x;
  const size_t stride = (size_t)Bb * KpPad * Hh;
  float s = 0.f;
#pragma unroll
  for (int sk = 0; sk < 4; ++sk)
    s += P[sk * stride + ((size_t)b * KpPad + k) * 128 + h];
  Hout[((size_t)b * Kp + k) * 128 + h] = s;
}

// ---------------- fp32 @W GEMM, K split in 2 ----------------
__global__ __launch_bounds__(256)
void wgemm_k(const float* __restrict__ A, long sA,
             const float* __restrict__ W,
             float* __restrict__ Cp)
{
  __shared__ float As[16][128];
  __shared__ float Bs[16][128];
  const int tid = threadIdx.x;
  const int p = blockIdx.x;
  const int b = blockIdx.z;
  const int m0 = blockIdx.y * 128;
  const int k0 = p * 64;
  const int ty = tid >> 4, tx = tid & 15;

  const float* Ab = A + (size_t)b * sA;

  float acc[8][8];
#pragma unroll
  for (int r = 0; r < 8; ++r)
#pragma unroll
    for (int c = 0; c < 8; ++c) acc[r][c] = 0.f;

  const int ai = tid >> 1;
  const int ak0 = (tid & 1) * 8;

  for (int kk0 = k0; kk0 < k0 + 64; kk0 += 16) {
    float av[8];
    load8<float>(Ab + (size_t)(m0 + ai) * Hh + kk0 + ak0, av);
    float bv[8];
    const int bk_row = tid >> 4, bj0 = (tid & 15) * 8;
    load8<float>(W + (size_t)(kk0 + bk_row) * Hh + bj0, bv);

    __syncthreads();
#pragma unroll
    for (int e = 0; e < 8; ++e) Bs[bk_row][bj0 + e] = bv[e];
#pragma unroll
    for (int e = 0; e < 8; ++e) As[ak0 + e][ai] = av[e];
    __syncthreads();

#pragma unroll
    for (int k = 0; k < 16; ++k) {
      const float4 a0 = *reinterpret_cast<const float4*>(&As[k][4 * ty]);
      const float4 a1 = *reinterpret_cast<const float4*>(&As[k][64 + 4 * ty]);
      const float4 b0 = *reinterpret_cast<const float4*>(&Bs[k][4 * tx]);
      const float4 b1 = *reinterpret_cast<const float4*>(&Bs[k][64 + 4 * tx]);
      const float ar[8] = {a0.x, a0.y, a0.z, a0.w, a1.x, a1.y, a1.z, a1.w};
      const float br[8] = {b0.x, b0.y, b0.z, b0.w, b1.x, b1.y, b1.z, b1.w};
#pragma unroll
      for (int r = 0; r < 8; ++r)
#pragma unroll
        for (int c = 0; c < 8; ++c)
          acc[r][c] = fmaf(ar[r], br[c], acc[r][c]);
    }
  }

  float* Cb = Cp + (size_t)p * Bb * Nn * Hh + (size_t)b * sA;
#pragma unroll
  for (int r = 0; r < 8; ++r) {
    const int gi = m0 + ((r < 4) ? (4 * ty + r) : (64 + 4 * ty + r - 4));
#pragma unroll
    for (int c = 0; c < 8; ++c) {
      const int gj = (c < 4) ? (4 * tx + c) : (64 + 4 * tx + c - 4);
      Cb[(size_t)gi * Hh + gj] = acc[r][c];
    }
  }
}

// ---------------- converters ----------------

__global__ __launch_bounds__(256)
void prep_k(const float* __restrict__ adj, const float* __restrict__ invc,
            __hip_bfloat16* __restrict__ S, __hip_bfloat16* __restrict__ At,
            float* __restrict__ pa)
{
  __shared__ float tile[32][36];
  const int b = blockIdx.z;
  const long j0 = (long)blockIdx.x * 32;
  const long ibase = (long)blockIdx.y * 64;
  const int r = threadIdx.x >> 3, c4 = (threadIdx.x & 7) * 4;
  const float4 ic = *(const float4*)(invc + (size_t)b * Nn + j0 + c4);
  float cs = 0.f;
#pragma unroll
  for (int st = 0; st < 2; ++st) {
    const long i0 = ibase + st * 32;
    const float4 v = *(const float4*)(adj + ((size_t)b * Nn + (i0 + r)) * Nn + j0 + c4);
    ushort4 sv;
    sv.x = f2bfbits(v.x * ic.x);
    sv.y = f2bfbits(v.y * ic.y);
    sv.z = f2bfbits(v.z * ic.z);
    sv.w = f2bfbits(v.w * ic.w);
    *(ushort4*)((unsigned short*)S + ((size_t)b * Nn + (i0 + r)) * Nn + j0 + c4) = sv;
    tile[r][c4 + 0] = v.x;
    tile[r][c4 + 1] = v.y;
    tile[r][c4 + 2] = v.z;
    tile[r][c4 + 3] = v.w;
    __syncthreads();
    ushort4 tv;
    tv.x = f2bfbits(tile[c4 + 0][r]);
    tv.y = f2bfbits(tile[c4 + 1][r]);
    tv.z = f2bfbits(tile[c4 + 2][r]);
    tv.w = f2bfbits(tile[c4 + 3][r]);
    *(ushort4*)((unsigned short*)At + ((size_t)b * Nn + (j0 + r)) * Nn + i0 + c4) = tv;
    if (threadIdx.x < 32) {
      float a = 0.f;
#pragma unroll
      for (int rr = 0; rr < 32; ++rr) a += tile[rr][threadIdx.x];
      cs += a;
    }
    __syncthreads();
  }
  if (threadIdx.x < 32)
    pa[(((size_t)b * 32 + blockIdx.y) << 11) + j0 + threadIdx.x] = cs;
}

__global__ __launch_bounds__(256)
void tconv2_k(const float* __restrict__ p0, const float* __restrict__ p1,
              long ld_src, long s_src,
              const float* __restrict__ scale, long scale_stride,
              __hip_bfloat16* __restrict__ dst, __hip_bfloat16* __restrict__ dlo,
              long ld_dst, long s_dst)
{
  __shared__ float tile[32][36];
  const int b = blockIdx.z;
  const long i0 = (long)blockIdx.y * 32, j0 = (long)blockIdx.x * 32;
  const int r = threadIdx.x >> 3, c4 = (threadIdx.x & 7) * 4;
  const size_t soff = (size_t)b * s_src + (i0 + r) * ld_src + j0 + c4;
  float4 v = *(const float4*)(p0 + soff);
  if (p1) {
    const float4 u = *(const float4*)(p1 + soff);
    v.x += u.x; v.y += u.y; v.z += u.z; v.w += u.w;
  }
  const float sc = scale[(size_t)b * scale_stride + i0 + r];
  tile[r][c4 + 0] = v.x * sc;
  tile[r][c4 + 1] = v.y * sc;
  tile[r][c4 + 2] = v.z * sc;
  tile[r][c4 + 3] = v.w * sc;
  __syncthreads();
  float t0 = tile[c4 + 0][r], t1 = tile[c4 + 1][r], t2 = tile[c4 + 2][r], t3 = tile[c4 + 3][r];
  ushort4 hi;
  hi.x = f2bfbits(t0); hi.y = f2bfbits(t1); hi.z = f2bfbits(t2); hi.w = f2bfbits(t3);
  const size_t doff = (size_t)b * s_dst + (j0 + r) * ld_dst + i0 + c4;
  *(ushort4*)((unsigned short*)dst + doff) = hi;
  ushort4 lo;
  lo.x = f2bfbits(t0 - bf2f(hi.x));
  lo.y = f2bfbits(t1 - bf2f(hi.y));
  lo.z = f2bfbits(t2 - bf2f(hi.z));
  lo.w = f2bfbits(t3 - bf2f(hi.w));
  *(ushort4*)((unsigned short*)dlo + doff) = lo;
}

// ---------------- parallel reductions ----------------

__global__ __launch_bounds__(256)
void colsum_c_part_k(const float* __restrict__ adj, const int* __restrict__ top,
                     float* __restrict__ pc)
{
  __shared__ int rows[180];
  const int b = blockIdx.z, ch = blockIdx.y;
  const int n = blockIdx.x * 256 + threadIdx.x;
  const int k0 = ch * 180;
  const int cnt = min(Kp - k0, 180);
  for (int k = threadIdx.x; k < cnt; k += 256) rows[k] = top[b * Kp + k0 + k];
  __syncthreads();
  const float* ab = adj + (size_t)b * Nn * Nn;
  float a0 = 0.f, a1 = 0.f, a2 = 0.f, a3 = 0.f;
  int k = 0;
  for (; k + 4 <= cnt; k += 4) {
    a0 += ab[(size_t)rows[k + 0] * Nn + n];
    a1 += ab[(size_t)rows[k + 1] * Nn + n];
    a2 += ab[(size_t)rows[k + 2] * Nn + n];
    a3 += ab[(size_t)rows[k + 3] * Nn + n];
  }
  for (; k < cnt; ++k) a0 += ab[(size_t)rows[k] * Nn + n];
  pc[(((size_t)b * 8 + ch) << 11) + n] = (a0 + a1) + (a2 + a3);
}

__global__ __launch_bounds__(256)
void invc_fin_k(const float* __restrict__ pc, float* __restrict__ invc,
                float* __restrict__ cvec)
{
  const int i = blockIdx.x * 256 + threadIdx.x;
  const int b = i >> 11, n = i & (Nn - 1);
  float s = 0.f;
#pragma unroll
  for (int ch = 0; ch < 8; ++ch) s += pc[(((size_t)b * 8 + ch) << 11) + n];
  const float c = s + kEps;
  cvec[i] = c;
  invc[i] = 1.f / c;
}

__global__ __launch_bounds__(256)
void csum_fin_k(const float* __restrict__ pa, float* __restrict__ csum)
{
  const int i = blockIdx.x * 256 + threadIdx.x;
  const int b = i >> 11, m = i & (Nn - 1);
  float s = 0.f;
#pragma unroll
  for (int ch = 0; ch < 32; ++ch) s += pa[(((size_t)b * 32 + ch) << 11) + m];
  csum[i] = s;
}

// denom from bf16 S: denom[n] = sum_m S[n,m]*(cvec*atte)[m]; diag = S[n,n]*cvec[n]
__global__ __launch_bounds__(256)
void denom2_k(const __hip_bfloat16* __restrict__ S, const float* __restrict__ ca,
              const float* __restrict__ cvec,
              float* __restrict__ denom, float* __restrict__ diag)
{
  const int b = blockIdx.y;
  const int w = threadIdx.x >> 6, lane = threadIdx.x & 63;
  const int n = blockIdx.x * 4 + w;
  const unsigned short* srow = (const unsigned short*)S + ((size_t)b * Nn + n) * Nn;
  const float* cap = ca + (size_t)b * Nn;
  float acc = 0.f;
#pragma unroll
  for (int j = 0; j < 4; ++j) {
    const int o = j * 512 + lane * 8;
    const uint4 u = *(const uint4*)(srow + o);
    const float4 c0 = *(const float4*)(cap + o);
    const float4 c1 = *(const float4*)(cap + o + 4);
    acc += bf2f(u.x & 0xffffu) * c0.x + bf2f(u.x >> 16) * c0.y
         + bf2f(u.y & 0xffffu) * c0.z + bf2f(u.y >> 16) * c0.w
         + bf2f(u.z & 0xffffu) * c1.x + bf2f(u.z >> 16) * c1.y
         + bf2f(u.w & 0xffffu) * c1.z + bf2f(u.w >> 16) * c1.w;
  }
#pragma unroll
  for (int o = 32; o; o >>= 1) acc += __shfl_down(acc, o, 64);
  if (lane == 0) {
    denom[(size_t)b * Nn + n] = acc;
    diag[(size_t)b * Nn + n] = bf2f(srow[n]) * cvec[(size_t)b * Nn + n];
  }
}

__global__ __launch_bounds__(128)
void readout_part_k(const float* __restrict__ hid, const float* __restrict__ mask,
                    float* __restrict__ rp)
{
  const int b = blockIdx.y, ch = blockIdx.x, h = threadIdx.x;
  const float* hp = hid + ((size_t)b * Nn + ch * 128) * Hh;
  const float* mp = mask + (size_t)b * Nn + ch * 128;
  float acc = 0.f;
#pragma unroll 1
  for (int r = 0; r < 128; ++r) acc += mp[r] * hp[(size_t)r * Hh + h];
  rp[(((size_t)b * 16 + ch) << 7) + h] = acc;
}

__global__ __launch_bounds__(128)
void readout_fin_k(const float* __restrict__ rp, const float* __restrict__ mask,
                   float* __restrict__ out)
{
  __shared__ float sm[128];
  const int b = blockIdx.x, h = threadIdx.x;
  float acc = 0.f;
#pragma unroll
  for (int ch = 0; ch < 16; ++ch) acc += rp[(((size_t)b * 16 + ch) << 7) + h];
  float ms = 0.f;
#pragma unroll
  for (int j = 0; j < 16; ++j) ms += mask[(size_t)b * Nn + h * 16 + j];
  sm[h] = ms;
  __syncthreads();
  for (int o = 64; o; o >>= 1) {
    if (h < o) sm[h] += sm[h + o];
    __syncthreads();
  }
  out[(size_t)b * Hh + h] = acc / sm[0];
}

// ---------------- attention scalars ----------------

__global__ __launch_bounds__(256)
void scores_k(const float* __restrict__ hidden, const float* __restrict__ wb,
              const float* __restrict__ mask, float* __restrict__ s)
{
  const int wid = threadIdx.x >> 6, lane = threadIdx.x & 63;
  const int row = blockIdx.x * 4 + wid;
  const float* hp = hidden + (size_t)row * Hh;
  float acc = hp[lane] * wb[lane] + hp[64 + lane] * wb[64 + lane];
#pragma unroll
  for (int o = 32; o; o >>= 1) acc += __shfl_down(acc, o, 64);
  if (lane == 0) s[row] = acc + (mask[row] - 1.f) * kBig;
}

__global__ __launch_bounds__(256)
void rowmax_k(const float* __restrict__ s, float* __restrict__ rmax)
{
  __shared__ float red[256];
  const int b = blockIdx.x;
  float m = -3.4e38f;
  for (int n = threadIdx.x; n < Nn; n += 256) m = fmaxf(m, s[b * Nn + n]);
  red[threadIdx.x] = m;
  __syncthreads();
  for (int o = 128; o; o >>= 1) {
    if (threadIdx.x < o) red[threadIdx.x] = fmaxf(red[threadIdx.x], red[threadIdx.x + o]);
    __syncthreads();
  }
  if (threadIdx.x == 0) rmax[b] = red[0];
}

__global__ __launch_bounds__(256)
void attexp_k(const float* __restrict__ s, const float* __restrict__ rmax,
              const float* __restrict__ tau, const float* __restrict__ cvec,
              float* __restrict__ atte, float* __restrict__ ca)
{
  const int i = blockIdx.x * 256 + threadIdx.x;
  const int b = i >> 11;
  const float e = expf((s[i] - rmax[b]) * fabsf(*tau));
  atte[i] = e;
  ca[i] = e * cvec[i];
}

// att = atte*diag/(denom+EPS)*csum*mask
__global__ __launch_bounds__(256)
void att_final_k(const float* __restrict__ atte, const float* __restrict__ diag,
                 const float* __restrict__ denom, const float* __restrict__ colsum,
                 const float* __restrict__ mask, float* __restrict__ att)
{
  const int i = blockIdx.x * 256 + threadIdx.x;
  att[i] = atte[i] * diag[i] / (denom[i] + kEps) * colsum[i] * mask[i];
}

__global__ __launch_bounds__(256)
void ones_k(float* __restrict__ p, int n)
{
  const int i = blockIdx.x * 256 + threadIdx.x;
  if (i < n) p[i] = 1.f;
}

}  // namespace

extern "C" void kernel_launch(void* const* d_in, const int* in_sizes, int n_in,
                              void* d_out, int out_size, void* d_ws, size_t ws_size,
                              hipStream_t stream) {
  const float* X    = (const float*)d_in[0];
  const float* adj  = (const float*)d_in[1];
  const float* mask = (const float*)d_in[2];
  const float* W1   = (const float*)d_in[3];
  const float* b1   = (const float*)d_in[4];
  const float* W2   = (const float*)d_in[5];
  const float* b2   = (const float*)d_in[6];
  const float* wb   = (const float*)d_in[7];
  const float* tau  = (const float*)d_in[8];
  const int*   top  = (const int*)d_in[9];
  float* out = (float*)d_out;

  // ws layout (float offsets)
  float* ws    = (float*)d_ws;
  float* h1hid = ws;                   // [B,N,H] f32
  float* Btf   = ws + 2097152;         // Bt hi/lo bf16 pair region (8MB)
  float* invc  = ws + 4194304;         // [B,N]
  float* cvec  = ws + 4210688;
  float* s     = ws + 4227072;
  float* atte  = ws + 4243456;
  float* den   = ws + 4259840;
  float* diag  = ws + 4276224;
  float* csum  = ws + 4292608;
  float* att   = ws + 4308992;
  float* ca    = ws + 4325376;
  float* rmax  = ws + 4341760;         // 256
  float* pc    = ws + 4342016;         // [B][8][N]   131072
  float* pa    = ws + 4473088;         // [B][32][N]  524288
  float* rp    = ws + 4997376;         // [B][16][H]  16384
  __hip_bfloat16* S   = (__hip_bfloat16*)(ws + 5013760);   // [B,N,N] bf16, 67.1MB
  __hip_bfloat16* At  = S + (size_t)Bb * Nn * Nn;          // 67.1MB: At bf16, later P f32
  float*          P   = (float*)At;                        // [4][B][Mpad][128] f32
  __hip_bfloat16* T   = At + (size_t)Bb * Nn * Nn;         // [B,1536,N] bf16, later Tpart f32
  float*          Tpart = (float*)T;                       // [2][B,2048,128] f32 = 16MB
  if (ws_size < 204604416u) return;    // ~204.6 MB scratch

  __hip_bfloat16* Bthi = (__hip_bfloat16*)Btf;             // [B,128,2048] bf16
  __hip_bfloat16* Btlo = Bthi + (size_t)Bb * Hh * Nn;

  float* Hout    = out + 1024;
  float* newadj  = out + 1469440;
  float* newmask = out + 17920288;

  const long sAdj = (long)Nn * Nn;
  const long sNH  = (long)Nn * Hh;
  const long sHN  = (long)Hh * Nn;
  const long sT   = (long)KpPad * Nn;
  const long sNew = (long)Kp * Kp;

  // 1. assign-column normalizer (split-K parallel) -> invc, cvec
  colsum_c_part_k<<<dim3(Nn / 256, 8, Bb), 256, 0, stream>>>(adj, top, pc);
  invc_fin_k<<<dim3(Bb * Nn / 256), 256, 0, stream>>>(pc, invc, cvec);

  // 2. fused prep: one adj read -> S = adj*invc[col], At = adj^T, pa = colsum partials
  prep_k<<<dim3(Nn / 32, Nn / 64, Bb), 256, 0, stream>>>(adj, invc, S, At, pa);
  csum_fin_k<<<dim3(Bb * Nn / 256), 256, 0, stream>>>(pa, csum);

  // 3. T = S(gathered) @ At^T ; new_adj = T @ S(gathered)^T  (XCD-swizzled, 32x32 MFMA)
  mgemm_k<__hip_bfloat16><<<dim3(Nn / 128, KpPad / 128, Bb), 256, 0, stream>>>(
      S, Nn, sAdj, At, Nn, sAdj, top, Kp, Kp, nullptr, 0, 0,
      T, Nn, sT, KpPad, Nn, Nn);
  mgemm_k<float><<<dim3(KpPad / 128, KpPad / 128, Bb), 256, 0, stream>>>(
      T, Nn, sT, S, Nn, sAdj, nullptr, 0, 0, top, Kp, Kp,
      newadj, Kp, sNew, Kp, Kp, Nn);
  // At region dead -> P ; T region dead -> Tpart

  // 4. GCN layer 1: XW1 = X@W1 (K-split-2); h1 = relu(S@(cvec.*XW1)+b1)
  wgemm_k<<<dim3(2, Nn / 128, Bb), 256, 0, stream>>>(X, sNH, W1, Tpart);
  tconv2_k<<<dim3(Hh / 32, Nn / 32, Bb), 256, 0, stream>>>(
      Tpart, Tpart + (size_t)Bb * Nn * Hh, Hh, sNH, cvec, Nn, Bthi, Btlo, Nn, sHN);
  mlayer2_k<false><<<dim3(4, Nn / 128, Bb), 256, 0, stream>>>(
      S, Nn, sAdj, Bthi, Btlo, Nn, sHN, nullptr, 0, 0, P, Nn, Nn / 4);
  red_layer_k<false><<<dim3(2048), 256, 0, stream>>>(P, b1, nullptr, h1hid);

  // 5. GCN layer 2
  wgemm_k<<<dim3(2, Nn / 128, Bb), 256, 0, stream>>>(h1hid, sNH, W2, Tpart);
  tconv2_k<<<dim3(Hh / 32, Nn / 32, Bb), 256, 0, stream>>>(
      Tpart, Tpart + (size_t)Bb * Nn * Hh, Hh, sNH, cvec, Nn, Bthi, Btlo, Nn, sHN);
  mlayer2_k<false><<<dim3(4, Nn / 128, Bb), 256, 0, stream>>>(
      S, Nn, sAdj, Bthi, Btlo, Nn, sHN, nullptr, 0, 0, P, Nn, Nn / 4);
  red_layer_k<true><<<dim3(2048), 256, 0, stream>>>(P, b2, mask, h1hid);

  // 6. attention scalars (denom/diag from bf16 S, half traffic)
  scores_k<<<dim3(Bb * Nn / 4), 256, 0, stream>>>(h1hid, wb, mask, s);
  rowmax_k<<<dim3(Bb), 256, 0, stream>>>(s, rmax);
  attexp_k<<<dim3(Bb * Nn / 256), 256, 0, stream>>>(s, rmax, tau, cvec, atte, ca);
  denom2_k<<<dim3(Nn / 4, Bb), 256, 0, stream>>>(S, ca, cvec, den, diag);
  att_final_k<<<dim3(Bb * Nn / 256), 256, 0, stream>>>(atte, diag, den, csum, mask, att);

  // 7. H_out = gather(S) @ (att .* hid)
  tconv2_k<<<dim3(Hh / 32, Nn / 32, Bb), 256, 0, stream>>>(
      h1hid, nullptr, Hh, sNH, att, Nn, Bthi, Btlo, Nn, sHN);
  mlayer2_k<true><<<dim3(4, KpPad / 128, Bb), 256, 0, stream>>>(
      S, Nn, sAdj, Bthi, Btlo, Nn, sHN, top, Kp, Kp, P, KpPad, Nn / 4);
  red_hout_k<<<dim3(Kp, Bb), 128, 0, stream>>>(P, Hout);

  // 8. readout + new_mask
  readout_part_k<<<dim3(16, Bb), 128, 0, stream>>>(h1hid, mask, rp);
  readout_fin_k<<<dim3(Bb), 128, 0, stream>>>(rp, mask, out);
  ones_k<<<dim3((Bb * Kp + 255) / 256), 256, 0, stream>>>(newmask, Bb * Kp);
}

// Round 9
// 466.906 us; speedup vs baseline: 1.1115x; 1.1115x over previous
//
#include <hip/hip_runtime.h>
#include <hip/hip_bf16.h>

namespace {

constexpr int Bb = 8;
constexpr int Nn = 2048;
constexpr int Hh = 128;
constexpr int Kp = 1434;
constexpr int KpPad = 1536;
constexpr float kEps = 1e-10f;
constexpr float kBig = 1e10f;

using bf16x8 = __attribute__((ext_vector_type(8))) short;
using f32x4  = __attribute__((ext_vector_type(4))) float;

__device__ __forceinline__ float bf2f(unsigned u) {
  union { float f; unsigned q; } x; x.q = u << 16; return x.f;
}

__device__ __forceinline__ unsigned short f2bfbits(float f) {
  __hip_bfloat16 h = __float2bfloat16(f);
  return *reinterpret_cast<unsigned short*>(&h);
}

template<typename TA>
__device__ __forceinline__ void load8(const TA* p, float v[8]) {
  const float4* q = reinterpret_cast<const float4*>(p);
  float4 x0 = q[0], x1 = q[1];
  v[0]=x0.x; v[1]=x0.y; v[2]=x0.z; v[3]=x0.w;
  v[4]=x1.x; v[5]=x1.y; v[6]=x1.z; v[7]=x1.w;
}

template<typename TC>
__device__ __forceinline__ TC cvt_out(float v) {
  if constexpr (sizeof(TC) == 2) {
    return __float2bfloat16(v);
  } else {
    return v;
  }
}

__device__ __forceinline__ void gload_lds16(const void* g, void* l) {
  __builtin_amdgcn_global_load_lds(
      (const __attribute__((address_space(1))) void*)g,
      (__attribute__((address_space(3))) void*)l, 16, 0, 0);
}

// ---------------- bf16 MFMA GEMM: C = A(row-gathered) @ Bt(row-gathered)^T ---------------
// validated round 7: 16x16x32 MFMA + bijective XCD-chunked swizzle (0 LDS conflicts).
// NOTE round-8 lesson: 32x32x16 fragment reads bank-conflict in this LDS layout — keep 16x16.
template<typename TC>
__global__ __launch_bounds__(256, 4)
void mgemm_k(const __hip_bfloat16* __restrict__ A, long lda, long sA,
             const __hip_bfloat16* __restrict__ Bt, long ldb, long sB,
             const int* __restrict__ ag, int ag_stride, int Mg,
             const int* __restrict__ bg, int bg_stride, int Ng,
             TC* __restrict__ C, long ldc, long sC,
             int Ms, int Ns, int Kd)
{
  __shared__ char smem[32768];
  char* smA = smem;
  char* smB = smem + 16384;
  const int t = threadIdx.x;

  // XCD-chunked bijective swizzle (nwg % 8 == 0 at all call sites)
  const int gx = gridDim.x, gy = gridDim.y;
  const int nwg = gx * gy * (int)gridDim.z;
  int lin = ((int)blockIdx.z * gy + (int)blockIdx.y) * gx + (int)blockIdx.x;
  lin = (lin & 7) * (nwg >> 3) + (lin >> 3);
  const int bx = lin % gx;
  const int by = (lin / gx) % gy;
  const int b  = lin / (gx * gy);

  const int m0 = by * 128, n0 = bx * 128;
  const int lane = t & 63, w = t >> 6;
  const int wr = w >> 1, wc = w & 1;

  const __hip_bfloat16* Ab = A + (size_t)b * sA;
  const __hip_bfloat16* Bb_ = Bt + (size_t)b * sB;

  const int srow = t >> 3;
  const int scol = ((t & 7) ^ (srow & 7)) * 16;
  const char* gA[4]; const char* gB[4];
#pragma unroll
  for (int q = 0; q < 4; ++q) {
    const int rowq = q * 32 + srow;
    long ga = m0 + rowq;
    if (ag) ga = (ga < Mg) ? (long)ag[(size_t)b * ag_stride + ga] : 0;
    gA[q] = (const char*)(Ab + ga * lda) + scol;
    long gb = n0 + rowq;
    if (bg) gb = (gb < Ng) ? (long)bg[(size_t)b * bg_stride + gb] : 0;
    gB[q] = (const char*)(Bb_ + gb * ldb) + scol;
  }

  f32x4 acc[4][4] = {};
  const int fr = lane & 15, kg = lane >> 4, fx = lane & 7;

  for (int kk = 0; kk < Kd; kk += 64) {
    __syncthreads();
#pragma unroll
    for (int q = 0; q < 4; ++q) {
      gload_lds16(gA[q] + (size_t)kk * 2, smA + q * 4096 + t * 16);
      gload_lds16(gB[q] + (size_t)kk * 2, smB + q * 4096 + t * 16);
    }
    __syncthreads();
#pragma unroll
    for (int ks = 0; ks < 2; ++ks) {
      bf16x8 aF[4], bF[4];
      const int slotbase = kg | (ks << 2);
#pragma unroll
      for (int mi = 0; mi < 4; ++mi) {
        const int off = (wr * 64 + mi * 16 + fr) * 128 + ((slotbase ^ fx) << 4);
        aF[mi] = *(const bf16x8*)(smA + off);
      }
#pragma unroll
      for (int ni = 0; ni < 4; ++ni) {
        const int off = (wc * 64 + ni * 16 + fr) * 128 + ((slotbase ^ fx) << 4);
        bF[ni] = *(const bf16x8*)(smB + off);
      }
#pragma unroll
      for (int mi = 0; mi < 4; ++mi)
#pragma unroll
        for (int ni = 0; ni < 4; ++ni)
          acc[mi][ni] = __builtin_amdgcn_mfma_f32_16x16x32_bf16(
              aF[mi], bF[ni], acc[mi][ni], 0, 0, 0);
    }
  }

  const int crow0 = m0 + wr * 64 + (lane >> 4) * 4;
  const int ccol0 = n0 + wc * 64 + fr;
#pragma unroll
  for (int mi = 0; mi < 4; ++mi) {
#pragma unroll
    for (int r = 0; r < 4; ++r) {
      const int row = crow0 + mi * 16 + r;
      if (row >= Ms) continue;
#pragma unroll
      for (int ni = 0; ni < 4; ++ni) {
        const int col = ccol0 + ni * 16;
        if (col >= Ns) continue;
        C[(size_t)b * sC + (size_t)row * ldc + col] = cvt_out<TC>(acc[mi][ni][r]);
      }
    }
  }
}

// ---------------- pure-bf16 layer MFMA (validated round 6/7; round 9: split-K = 4) -------
template<bool GATHER>
__global__ __launch_bounds__(256, 3)
void mlayer2_k(const __hip_bfloat16* __restrict__ A, long lda, long sA,
               const __hip_bfloat16* __restrict__ Bhi,
               const __hip_bfloat16* __restrict__ Blo, long ldb, long sB,
               const int* __restrict__ ag, int ag_stride, int Mg,
               float* __restrict__ P, int Mpad, int Kchunk)
{
  __shared__ char smem[49152];
  char* smA   = smem;
  char* smBhi = smem + 16384;
  char* smBlo = smem + 32768;
  const int t = threadIdx.x;
  const int b = blockIdx.z;
  const int sk = blockIdx.x;
  const int m0 = blockIdx.y * 128;
  const int k0 = sk * Kchunk;
  const int lane = t & 63, w = t >> 6;
  const int wr = w >> 1, wc = w & 1;

  const int srow = t >> 3;
  const int scol = ((t & 7) ^ (srow & 7)) * 16;
  const char* gA[4]; const char* gBhi[4]; const char* gBlo[4];
#pragma unroll
  for (int q = 0; q < 4; ++q) {
    const int rowq = q * 32 + srow;
    long ga = m0 + rowq;
    if (GATHER) ga = (ga < Mg) ? (long)ag[(size_t)b * ag_stride + ga] : 0;
    gA[q]   = (const char*)(A + (size_t)b * sA + ga * lda + k0) + scol;
    gBhi[q] = (const char*)(Bhi + (size_t)b * sB + (size_t)rowq * ldb + k0) + scol;
    gBlo[q] = (const char*)(Blo + (size_t)b * sB + (size_t)rowq * ldb + k0) + scol;
  }

  f32x4 acc[4][4] = {};
  const int fr = lane & 15, kg = lane >> 4, fx = lane & 7;

  for (int ks = 0; ks < Kchunk; ks += 64) {
    __syncthreads();
#pragma unroll
    for (int q = 0; q < 4; ++q) {
      gload_lds16(gA[q]   + (size_t)ks * 2, smA   + q * 4096 + t * 16);
      gload_lds16(gBhi[q] + (size_t)ks * 2, smBhi + q * 4096 + t * 16);
      gload_lds16(gBlo[q] + (size_t)ks * 2, smBlo + q * 4096 + t * 16);
    }
    __syncthreads();
#pragma unroll
    for (int ks2 = 0; ks2 < 2; ++ks2) {
      bf16x8 aF[4];
      const int slotbase = kg | (ks2 << 2);
#pragma unroll
      for (int mi = 0; mi < 4; ++mi) {
        const int off = (wr * 64 + mi * 16 + fr) * 128 + ((slotbase ^ fx) << 4);
        aF[mi] = *(const bf16x8*)(smA + off);
      }
#pragma unroll
      for (int ni = 0; ni < 4; ++ni) {
        const int off = (wc * 64 + ni * 16 + fr) * 128 + ((slotbase ^ fx) << 4);
        const bf16x8 bhi = *(const bf16x8*)(smBhi + off);
        const bf16x8 blo = *(const bf16x8*)(smBlo + off);
#pragma unroll
        for (int mi = 0; mi < 4; ++mi) {
          acc[mi][ni] = __builtin_amdgcn_mfma_f32_16x16x32_bf16(aF[mi], bhi, acc[mi][ni], 0, 0, 0);
          acc[mi][ni] = __builtin_amdgcn_mfma_f32_16x16x32_bf16(aF[mi], blo, acc[mi][ni], 0, 0, 0);
        }
      }
    }
  }

  float* Pp = P + ((size_t)sk * Bb + b) * Mpad * 128;
  const int crow0 = m0 + wr * 64 + (lane >> 4) * 4;
  const int ccol0 = wc * 64 + fr;
#pragma unroll
  for (int mi = 0; mi < 4; ++mi)
#pragma unroll
    for (int r = 0; r < 4; ++r) {
      const int row = crow0 + mi * 16 + r;
#pragma unroll
      for (int ni = 0; ni < 4; ++ni)
        Pp[(size_t)row * 128 + ccol0 + ni * 16] = acc[mi][ni][r];
    }
}

// ---------------- split-K reduce (sk = 4) ----------------
template<bool MASKED>
__global__ __launch_bounds__(256)
void red_layer_k(const float* __restrict__ P, const float* __restrict__ bias,
                 const float* __restrict__ mask, float* __restrict__ out)
{
  const size_t o = ((size_t)blockIdx.x * 256 + threadIdx.x) * 4;
  const size_t stride = (size_t)Bb * Nn * Hh;
  float4 s = {0.f, 0.f, 0.f, 0.f};
#pragma unroll
  for (int sk = 0; sk < 4; ++sk) {
    const float4 v = *(const float4*)(P + sk * stride + o);
    s.x += v.x; s.y += v.y; s.z += v.z; s.w += v.w;
  }
  const int h = (int)(o & 127);
  const float4 bi = *(const float4*)(bias + h);
  s.x = fmaxf(s.x + bi.x, 0.f);
  s.y = fmaxf(s.y + bi.y, 0.f);
  s.z = fmaxf(s.z + bi.z, 0.f);
  s.w = fmaxf(s.w + bi.w, 0.f);
  if (MASKED) {
    const int n = (int)((o >> 7) & (Nn - 1));
    const int b = (int)(o >> 18);
    const float m = mask[b * Nn + n];
    s.x *= m; s.y *= m; s.z *= m; s.w *= m;
  }
  *(float4*)(out + o) = s;
}

__global__ __launch_bounds__(128)
void red_hout_k(const float* __restrict__ P, float* __restrict__ Hout)
{
  const int k = blockIdx.x, b = blockIdx.y, h = threadIdx.x;
  const size_t stride = (size_t)Bb * KpPad * Hh;
  float s = 0.f;
#pragma unroll
  for (int sk = 0; sk < 4; ++sk)
    s += P[sk * stride + ((size_t)b * KpPad + k) * 128 + h];
  Hout[((size_t)b * Kp + k) * 128 + h] = s;
}

// ---------------- fp32 @W GEMM, K split in 2 ----------------
__global__ __launch_bounds__(256)
void wgemm_k(const float* __restrict__ A, long sA,
             const float* __restrict__ W,
             float* __restrict__ Cp)
{
  __shared__ float As[16][128];
  __shared__ float Bs[16][128];
  const int tid = threadIdx.x;
  const int p = blockIdx.x;
  const int b = blockIdx.z;
  const int m0 = blockIdx.y * 128;
  const int k0 = p * 64;
  const int ty = tid >> 4, tx = tid & 15;

  const float* Ab = A + (size_t)b * sA;

  float acc[8][8];
#pragma unroll
  for (int r = 0; r < 8; ++r)
#pragma unroll
    for (int c = 0; c < 8; ++c) acc[r][c] = 0.f;

  const int ai = tid >> 1;
  const int ak0 = (tid & 1) * 8;

  for (int kk0 = k0; kk0 < k0 + 64; kk0 += 16) {
    float av[8];
    load8<float>(Ab + (size_t)(m0 + ai) * Hh + kk0 + ak0, av);
    float bv[8];
    const int bk_row = tid >> 4, bj0 = (tid & 15) * 8;
    load8<float>(W + (size_t)(kk0 + bk_row) * Hh + bj0, bv);

    __syncthreads();
#pragma unroll
    for (int e = 0; e < 8; ++e) Bs[bk_row][bj0 + e] = bv[e];
#pragma unroll
    for (int e = 0; e < 8; ++e) As[ak0 + e][ai] = av[e];
    __syncthreads();

#pragma unroll
    for (int k = 0; k < 16; ++k) {
      const float4 a0 = *reinterpret_cast<const float4*>(&As[k][4 * ty]);
      const float4 a1 = *reinterpret_cast<const float4*>(&As[k][64 + 4 * ty]);
      const float4 b0 = *reinterpret_cast<const float4*>(&Bs[k][4 * tx]);
      const float4 b1 = *reinterpret_cast<const float4*>(&Bs[k][64 + 4 * tx]);
      const float ar[8] = {a0.x, a0.y, a0.z, a0.w, a1.x, a1.y, a1.z, a1.w};
      const float br[8] = {b0.x, b0.y, b0.z, b0.w, b1.x, b1.y, b1.z, b1.w};
#pragma unroll
      for (int r = 0; r < 8; ++r)
#pragma unroll
        for (int c = 0; c < 8; ++c)
          acc[r][c] = fmaf(ar[r], br[c], acc[r][c]);
    }
  }

  float* Cb = Cp + (size_t)p * Bb * Nn * Hh + (size_t)b * sA;
#pragma unroll
  for (int r = 0; r < 8; ++r) {
    const int gi = m0 + ((r < 4) ? (4 * ty + r) : (64 + 4 * ty + r - 4));
#pragma unroll
    for (int c = 0; c < 8; ++c) {
      const int gj = (c < 4) ? (4 * tx + c) : (64 + 4 * tx + c - 4);
      Cb[(size_t)gi * Hh + gj] = acc[r][c];
    }
  }
}

// ---------------- converters ----------------

__global__ __launch_bounds__(256)
void prep_k(const float* __restrict__ adj, const float* __restrict__ invc,
            __hip_bfloat16* __restrict__ S, __hip_bfloat16* __restrict__ At,
            float* __restrict__ pa)
{
  __shared__ float tile[32][36];
  const int b = blockIdx.z;
  const long j0 = (long)blockIdx.x * 32;
  const long ibase = (long)blockIdx.y * 64;
  const int r = threadIdx.x >> 3, c4 = (threadIdx.x & 7) * 4;
  const float4 ic = *(const float4*)(invc + (size_t)b * Nn + j0 + c4);
  float cs = 0.f;
#pragma unroll
  for (int st = 0; st < 2; ++st) {
    const long i0 = ibase + st * 32;
    const float4 v = *(const float4*)(adj + ((size_t)b * Nn + (i0 + r)) * Nn + j0 + c4);
    ushort4 sv;
    sv.x = f2bfbits(v.x * ic.x);
    sv.y = f2bfbits(v.y * ic.y);
    sv.z = f2bfbits(v.z * ic.z);
    sv.w = f2bfbits(v.w * ic.w);
    *(ushort4*)((unsigned short*)S + ((size_t)b * Nn + (i0 + r)) * Nn + j0 + c4) = sv;
    tile[r][c4 + 0] = v.x;
    tile[r][c4 + 1] = v.y;
    tile[r][c4 + 2] = v.z;
    tile[r][c4 + 3] = v.w;
    __syncthreads();
    ushort4 tv;
    tv.x = f2bfbits(tile[c4 + 0][r]);
    tv.y = f2bfbits(tile[c4 + 1][r]);
    tv.z = f2bfbits(tile[c4 + 2][r]);
    tv.w = f2bfbits(tile[c4 + 3][r]);
    *(ushort4*)((unsigned short*)At + ((size_t)b * Nn + (j0 + r)) * Nn + i0 + c4) = tv;
    if (threadIdx.x < 32) {
      float a = 0.f;
#pragma unroll
      for (int rr = 0; rr < 32; ++rr) a += tile[rr][threadIdx.x];
      cs += a;
    }
    __syncthreads();
  }
  if (threadIdx.x < 32)
    pa[(((size_t)b * 32 + blockIdx.y) << 11) + j0 + threadIdx.x] = cs;
}

__global__ __launch_bounds__(256)
void tconv2_k(const float* __restrict__ p0, const float* __restrict__ p1,
              long ld_src, long s_src,
              const float* __restrict__ scale, long scale_stride,
              __hip_bfloat16* __restrict__ dst, __hip_bfloat16* __restrict__ dlo,
              long ld_dst, long s_dst)
{
  __shared__ float tile[32][36];
  const int b = blockIdx.z;
  const long i0 = (long)blockIdx.y * 32, j0 = (long)blockIdx.x * 32;
  const int r = threadIdx.x >> 3, c4 = (threadIdx.x & 7) * 4;
  const size_t soff = (size_t)b * s_src + (i0 + r) * ld_src + j0 + c4;
  float4 v = *(const float4*)(p0 + soff);
  if (p1) {
    const float4 u = *(const float4*)(p1 + soff);
    v.x += u.x; v.y += u.y; v.z += u.z; v.w += u.w;
  }
  const float sc = scale[(size_t)b * scale_stride + i0 + r];
  tile[r][c4 + 0] = v.x * sc;
  tile[r][c4 + 1] = v.y * sc;
  tile[r][c4 + 2] = v.z * sc;
  tile[r][c4 + 3] = v.w * sc;
  __syncthreads();
  float t0 = tile[c4 + 0][r], t1 = tile[c4 + 1][r], t2 = tile[c4 + 2][r], t3 = tile[c4 + 3][r];
  ushort4 hi;
  hi.x = f2bfbits(t0); hi.y = f2bfbits(t1); hi.z = f2bfbits(t2); hi.w = f2bfbits(t3);
  const size_t doff = (size_t)b * s_dst + (j0 + r) * ld_dst + i0 + c4;
  *(ushort4*)((unsigned short*)dst + doff) = hi;
  ushort4 lo;
  lo.x = f2bfbits(t0 - bf2f(hi.x));
  lo.y = f2bfbits(t1 - bf2f(hi.y));
  lo.z = f2bfbits(t2 - bf2f(hi.z));
  lo.w = f2bfbits(t3 - bf2f(hi.w));
  *(ushort4*)((unsigned short*)dlo + doff) = lo;
}

// ---------------- parallel reductions ----------------

__global__ __launch_bounds__(256)
void colsum_c_part_k(const float* __restrict__ adj, const int* __restrict__ top,
                     float* __restrict__ pc)
{
  __shared__ int rows[180];
  const int b = blockIdx.z, ch = blockIdx.y;
  const int n = blockIdx.x * 256 + threadIdx.x;
  const int k0 = ch * 180;
  const int cnt = min(Kp - k0, 180);
  for (int k = threadIdx.x; k < cnt; k += 256) rows[k] = top[b * Kp + k0 + k];
  __syncthreads();
  const float* ab = adj + (size_t)b * Nn * Nn;
  float a0 = 0.f, a1 = 0.f, a2 = 0.f, a3 = 0.f;
  int k = 0;
  for (; k + 4 <= cnt; k += 4) {
    a0 += ab[(size_t)rows[k + 0] * Nn + n];
    a1 += ab[(size_t)rows[k + 1] * Nn + n];
    a2 += ab[(size_t)rows[k + 2] * Nn + n];
    a3 += ab[(size_t)rows[k + 3] * Nn + n];
  }
  for (; k < cnt; ++k) a0 += ab[(size_t)rows[k] * Nn + n];
  pc[(((size_t)b * 8 + ch) << 11) + n] = (a0 + a1) + (a2 + a3);
}

__global__ __launch_bounds__(256)
void invc_fin_k(const float* __restrict__ pc, float* __restrict__ invc,
                float* __restrict__ cvec)
{
  const int i = blockIdx.x * 256 + threadIdx.x;
  const int b = i >> 11, n = i & (Nn - 1);
  float s = 0.f;
#pragma unroll
  for (int ch = 0; ch < 8; ++ch) s += pc[(((size_t)b * 8 + ch) << 11) + n];
  const float c = s + kEps;
  cvec[i] = c;
  invc[i] = 1.f / c;
}

__global__ __launch_bounds__(256)
void csum_fin_k(const float* __restrict__ pa, float* __restrict__ csum)
{
  const int i = blockIdx.x * 256 + threadIdx.x;
  const int b = i >> 11, m = i & (Nn - 1);
  float s = 0.f;
#pragma unroll
  for (int ch = 0; ch < 32; ++ch) s += pa[(((size_t)b * 32 + ch) << 11) + m];
  csum[i] = s;
}

// denom from bf16 S: denom[n] = sum_m S[n,m]*(cvec*atte)[m]; diag = S[n,n]*cvec[n]
__global__ __launch_bounds__(256)
void denom2_k(const __hip_bfloat16* __restrict__ S, const float* __restrict__ ca,
              const float* __restrict__ cvec,
              float* __restrict__ denom, float* __restrict__ diag)
{
  const int b = blockIdx.y;
  const int w = threadIdx.x >> 6, lane = threadIdx.x & 63;
  const int n = blockIdx.x * 4 + w;
  const unsigned short* srow = (const unsigned short*)S + ((size_t)b * Nn + n) * Nn;
  const float* cap = ca + (size_t)b * Nn;
  float acc = 0.f;
#pragma unroll
  for (int j = 0; j < 4; ++j) {
    const int o = j * 512 + lane * 8;
    const uint4 u = *(const uint4*)(srow + o);
    const float4 c0 = *(const float4*)(cap + o);
    const float4 c1 = *(const float4*)(cap + o + 4);
    acc += bf2f(u.x & 0xffffu) * c0.x + bf2f(u.x >> 16) * c0.y
         + bf2f(u.y & 0xffffu) * c0.z + bf2f(u.y >> 16) * c0.w
         + bf2f(u.z & 0xffffu) * c1.x + bf2f(u.z >> 16) * c1.y
         + bf2f(u.w & 0xffffu) * c1.z + bf2f(u.w >> 16) * c1.w;
  }
#pragma unroll
  for (int o = 32; o; o >>= 1) acc += __shfl_down(acc, o, 64);
  if (lane == 0) {
    denom[(size_t)b * Nn + n] = acc;
    diag[(size_t)b * Nn + n] = bf2f(srow[n]) * cvec[(size_t)b * Nn + n];
  }
}

__global__ __launch_bounds__(128)
void readout_part_k(const float* __restrict__ hid, const float* __restrict__ mask,
                    float* __restrict__ rp)
{
  const int b = blockIdx.y, ch = blockIdx.x, h = threadIdx.x;
  const float* hp = hid + ((size_t)b * Nn + ch * 128) * Hh;
  const float* mp = mask + (size_t)b * Nn + ch * 128;
  float acc = 0.f;
#pragma unroll 1
  for (int r = 0; r < 128; ++r) acc += mp[r] * hp[(size_t)r * Hh + h];
  rp[(((size_t)b * 16 + ch) << 7) + h] = acc;
}

__global__ __launch_bounds__(128)
void readout_fin_k(const float* __restrict__ rp, const float* __restrict__ mask,
                   float* __restrict__ out)
{
  __shared__ float sm[128];
  const int b = blockIdx.x, h = threadIdx.x;
  float acc = 0.f;
#pragma unroll
  for (int ch = 0; ch < 16; ++ch) acc += rp[(((size_t)b * 16 + ch) << 7) + h];
  float ms = 0.f;
#pragma unroll
  for (int j = 0; j < 16; ++j) ms += mask[(size_t)b * Nn + h * 16 + j];
  sm[h] = ms;
  __syncthreads();
  for (int o = 64; o; o >>= 1) {
    if (h < o) sm[h] += sm[h + o];
    __syncthreads();
  }
  out[(size_t)b * Hh + h] = acc / sm[0];
}

// ---------------- attention scalars ----------------

__global__ __launch_bounds__(256)
void scores_k(const float* __restrict__ hidden, const float* __restrict__ wb,
              const float* __restrict__ mask, float* __restrict__ s)
{
  const int wid = threadIdx.x >> 6, lane = threadIdx.x & 63;
  const int row = blockIdx.x * 4 + wid;
  const float* hp = hidden + (size_t)row * Hh;
  float acc = hp[lane] * wb[lane] + hp[64 + lane] * wb[64 + lane];
#pragma unroll
  for (int o = 32; o; o >>= 1) acc += __shfl_down(acc, o, 64);
  if (lane == 0) s[row] = acc + (mask[row] - 1.f) * kBig;
}

__global__ __launch_bounds__(256)
void rowmax_k(const float* __restrict__ s, float* __restrict__ rmax)
{
  __shared__ float red[256];
  const int b = blockIdx.x;
  float m = -3.4e38f;
  for (int n = threadIdx.x; n < Nn; n += 256) m = fmaxf(m, s[b * Nn + n]);
  red[threadIdx.x] = m;
  __syncthreads();
  for (int o = 128; o; o >>= 1) {
    if (threadIdx.x < o) red[threadIdx.x] = fmaxf(red[threadIdx.x], red[threadIdx.x + o]);
    __syncthreads();
  }
  if (threadIdx.x == 0) rmax[b] = red[0];
}

__global__ __launch_bounds__(256)
void attexp_k(const float* __restrict__ s, const float* __restrict__ rmax,
              const float* __restrict__ tau, const float* __restrict__ cvec,
              float* __restrict__ atte, float* __restrict__ ca)
{
  const int i = blockIdx.x * 256 + threadIdx.x;
  const int b = i >> 11;
  const float e = expf((s[i] - rmax[b]) * fabsf(*tau));
  atte[i] = e;
  ca[i] = e * cvec[i];
}

// att = atte*diag/(denom+EPS)*csum*mask
__global__ __launch_bounds__(256)
void att_final_k(const float* __restrict__ atte, const float* __restrict__ diag,
                 const float* __restrict__ denom, const float* __restrict__ colsum,
                 const float* __restrict__ mask, float* __restrict__ att)
{
  const int i = blockIdx.x * 256 + threadIdx.x;
  att[i] = atte[i] * diag[i] / (denom[i] + kEps) * colsum[i] * mask[i];
}

__global__ __launch_bounds__(256)
void ones_k(float* __restrict__ p, int n)
{
  const int i = blockIdx.x * 256 + threadIdx.x;
  if (i < n) p[i] = 1.f;
}

}  // namespace

extern "C" void kernel_launch(void* const* d_in, const int* in_sizes, int n_in,
                              void* d_out, int out_size, void* d_ws, size_t ws_size,
                              hipStream_t stream) {
  const float* X    = (const float*)d_in[0];
  const float* adj  = (const float*)d_in[1];
  const float* mask = (const float*)d_in[2];
  const float* W1   = (const float*)d_in[3];
  const float* b1   = (const float*)d_in[4];
  const float* W2   = (const float*)d_in[5];
  const float* b2   = (const float*)d_in[6];
  const float* wb   = (const float*)d_in[7];
  const float* tau  = (const float*)d_in[8];
  const int*   top  = (const int*)d_in[9];
  float* out = (float*)d_out;

  // ws layout (float offsets)
  float* ws    = (float*)d_ws;
  float* h1hid = ws;                   // [B,N,H] f32
  float* Btf   = ws + 2097152;         // Bt hi/lo bf16 pair region (8MB)
  float* invc  = ws + 4194304;         // [B,N]
  float* cvec  = ws + 4210688;
  float* s     = ws + 4227072;
  float* atte  = ws + 4243456;
  float* den   = ws + 4259840;
  float* diag  = ws + 4276224;
  float* csum  = ws + 4292608;
  float* att   = ws + 4308992;
  float* ca    = ws + 4325376;
  float* rmax  = ws + 4341760;         // 256
  float* pc    = ws + 4342016;         // [B][8][N]   131072
  float* pa    = ws + 4473088;         // [B][32][N]  524288
  float* rp    = ws + 4997376;         // [B][16][H]  16384
  __hip_bfloat16* S   = (__hip_bfloat16*)(ws + 5013760);   // [B,N,N] bf16, 67.1MB
  __hip_bfloat16* At  = S + (size_t)Bb * Nn * Nn;          // 67.1MB: At bf16, later P f32
  float*          P   = (float*)At;                        // [4][B][Mpad][128] f32
  __hip_bfloat16* T   = At + (size_t)Bb * Nn * Nn;         // [B,1536,N] bf16, later Tpart f32
  float*          Tpart = (float*)T;                       // [2][B,2048,128] f32 = 16MB
  if (ws_size < 204604416u) return;    // ~204.6 MB scratch

  __hip_bfloat16* Bthi = (__hip_bfloat16*)Btf;             // [B,128,2048] bf16
  __hip_bfloat16* Btlo = Bthi + (size_t)Bb * Hh * Nn;

  float* Hout    = out + 1024;
  float* newadj  = out + 1469440;
  float* newmask = out + 17920288;

  const long sAdj = (long)Nn * Nn;
  const long sNH  = (long)Nn * Hh;
  const long sHN  = (long)Hh * Nn;
  const long sT   = (long)KpPad * Nn;
  const long sNew = (long)Kp * Kp;

  // 1. assign-column normalizer (split-K parallel) -> invc, cvec
  colsum_c_part_k<<<dim3(Nn / 256, 8, Bb), 256, 0, stream>>>(adj, top, pc);
  invc_fin_k<<<dim3(Bb * Nn / 256), 256, 0, stream>>>(pc, invc, cvec);

  // 2. fused prep: one adj read -> S = adj*invc[col], At = adj^T, pa = colsum partials
  prep_k<<<dim3(Nn / 32, Nn / 64, Bb), 256, 0, stream>>>(adj, invc, S, At, pa);
  csum_fin_k<<<dim3(Bb * Nn / 256), 256, 0, stream>>>(pa, csum);

  // 3. T = S(gathered) @ At^T ; new_adj = T @ S(gathered)^T  (XCD-swizzled, 16x16 MFMA)
  mgemm_k<__hip_bfloat16><<<dim3(Nn / 128, KpPad / 128, Bb), 256, 0, stream>>>(
      S, Nn, sAdj, At, Nn, sAdj, top, Kp, Kp, nullptr, 0, 0,
      T, Nn, sT, KpPad, Nn, Nn);
  mgemm_k<float><<<dim3(KpPad / 128, KpPad / 128, Bb), 256, 0, stream>>>(
      T, Nn, sT, S, Nn, sAdj, nullptr, 0, 0, top, Kp, Kp,
      newadj, Kp, sNew, Kp, Kp, Nn);
  // At region dead -> P ; T region dead -> Tpart

  // 4. GCN layer 1: XW1 = X@W1 (K-split-2); h1 = relu(S@(cvec.*XW1)+b1)
  wgemm_k<<<dim3(2, Nn / 128, Bb), 256, 0, stream>>>(X, sNH, W1, Tpart);
  tconv2_k<<<dim3(Hh / 32, Nn / 32, Bb), 256, 0, stream>>>(
      Tpart, Tpart + (size_t)Bb * Nn * Hh, Hh, sNH, cvec, Nn, Bthi, Btlo, Nn, sHN);
  mlayer2_k<false><<<dim3(4, Nn / 128, Bb), 256, 0, stream>>>(
      S, Nn, sAdj, Bthi, Btlo, Nn, sHN, nullptr, 0, 0, P, Nn, Nn / 4);
  red_layer_k<false><<<dim3(2048), 256, 0, stream>>>(P, b1, nullptr, h1hid);

  // 5. GCN layer 2
  wgemm_k<<<dim3(2, Nn / 128, Bb), 256, 0, stream>>>(h1hid, sNH, W2, Tpart);
  tconv2_k<<<dim3(Hh / 32, Nn / 32, Bb), 256, 0, stream>>>(
      Tpart, Tpart + (size_t)Bb * Nn * Hh, Hh, sNH, cvec, Nn, Bthi, Btlo, Nn, sHN);
  mlayer2_k<false><<<dim3(4, Nn / 128, Bb), 256, 0, stream>>>(
      S, Nn, sAdj, Bthi, Btlo, Nn, sHN, nullptr, 0, 0, P, Nn, Nn / 4);
  red_layer_k<true><<<dim3(2048), 256, 0, stream>>>(P, b2, mask, h1hid);

  // 6. attention scalars (denom/diag from bf16 S, half traffic)
  scores_k<<<dim3(Bb * Nn / 4), 256, 0, stream>>>(h1hid, wb, mask, s);
  rowmax_k<<<dim3(Bb), 256, 0, stream>>>(s, rmax);
  attexp_k<<<dim3(Bb * Nn / 256), 256, 0, stream>>>(s, rmax, tau, cvec, atte, ca);
  denom2_k<<<dim3(Nn / 4, Bb), 256, 0, stream>>>(S, ca, cvec, den, diag);
  att_final_k<<<dim3(Bb * Nn / 256), 256, 0, stream>>>(atte, diag, den, csum, mask, att);

  // 7. H_out = gather(S) @ (att .* hid)
  tconv2_k<<<dim3(Hh / 32, Nn / 32, Bb), 256, 0, stream>>>(
      h1hid, nullptr, Hh, sNH, att, Nn, Bthi, Btlo, Nn, sHN);
  mlayer2_k<true><<<dim3(4, KpPad / 128, Bb), 256, 0, stream>>>(
      S, Nn, sAdj, Bthi, Btlo, Nn, sHN, top, Kp, Kp, P, KpPad, Nn / 4);
  red_hout_k<<<dim3(Kp, Bb), 128, 0, stream>>>(P, Hout);

  // 8. readout + new_mask
  readout_part_k<<<dim3(16, Bb), 128, 0, stream>>>(h1hid, mask, rp);
  readout_fin_k<<<dim3(Bb), 128, 0, stream>>>(rp, mask, out);
  ones_k<<<dim3((Bb * Kp + 255) / 256), 256, 0, stream>>>(newmask, Bb * Kp);
}

// Round 10
// 457.110 us; speedup vs baseline: 1.1353x; 1.0214x over previous
//
#include <hip/hip_runtime.h>
#include <hip/hip_bf16.h>

namespace {

constexpr int Bb = 8;
constexpr int Nn = 2048;
constexpr int Hh = 128;
constexpr int Kp = 1434;
constexpr int KpPad = 1536;
constexpr float kEps = 1e-10f;
constexpr float kBig = 1e10f;

using bf16x8 = __attribute__((ext_vector_type(8))) short;
using f32x4  = __attribute__((ext_vector_type(4))) float;

__device__ __forceinline__ float bf2f(unsigned u) {
  union { float f; unsigned q; } x; x.q = u << 16; return x.f;
}

__device__ __forceinline__ unsigned short f2bfbits(float f) {
  __hip_bfloat16 h = __float2bfloat16(f);
  return *reinterpret_cast<unsigned short*>(&h);
}

template<typename TA>
__device__ __forceinline__ void load8(const TA* p, float v[8]) {
  const float4* q = reinterpret_cast<const float4*>(p);
  float4 x0 = q[0], x1 = q[1];
  v[0]=x0.x; v[1]=x0.y; v[2]=x0.z; v[3]=x0.w;
  v[4]=x1.x; v[5]=x1.y; v[6]=x1.z; v[7]=x1.w;
}

template<typename TC>
__device__ __forceinline__ TC cvt_out(float v) {
  if constexpr (sizeof(TC) == 2) {
    return __float2bfloat16(v);
  } else {
    return v;
  }
}

__device__ __forceinline__ void gload_lds16(const void* g, void* l) {
  __builtin_amdgcn_global_load_lds(
      (const __attribute__((address_space(1))) void*)g,
      (__attribute__((address_space(3))) void*)l, 16, 0, 0);
}

// ---------------- bf16 MFMA GEMM: C = A(row-gathered) @ Bt(row-gathered)^T ---------------
// validated round 7: 16x16x32 MFMA + bijective XCD-chunked swizzle (0 LDS conflicts).
// round-8 lesson: 32x32x16 fragment reads bank-conflict in this LDS layout — keep 16x16.
template<typename TC>
__global__ __launch_bounds__(256, 4)
void mgemm_k(const __hip_bfloat16* __restrict__ A, long lda, long sA,
             const __hip_bfloat16* __restrict__ Bt, long ldb, long sB,
             const int* __restrict__ ag, int ag_stride, int Mg,
             const int* __restrict__ bg, int bg_stride, int Ng,
             TC* __restrict__ C, long ldc, long sC,
             int Ms, int Ns, int Kd)
{
  __shared__ char smem[32768];
  char* smA = smem;
  char* smB = smem + 16384;
  const int t = threadIdx.x;

  // XCD-chunked bijective swizzle (nwg % 8 == 0 at all call sites)
  const int gx = gridDim.x, gy = gridDim.y;
  const int nwg = gx * gy * (int)gridDim.z;
  int lin = ((int)blockIdx.z * gy + (int)blockIdx.y) * gx + (int)blockIdx.x;
  lin = (lin & 7) * (nwg >> 3) + (lin >> 3);
  const int bx = lin % gx;
  const int by = (lin / gx) % gy;
  const int b  = lin / (gx * gy);

  const int m0 = by * 128, n0 = bx * 128;
  const int lane = t & 63, w = t >> 6;
  const int wr = w >> 1, wc = w & 1;

  const __hip_bfloat16* Ab = A + (size_t)b * sA;
  const __hip_bfloat16* Bb_ = Bt + (size_t)b * sB;

  const int srow = t >> 3;
  const int scol = ((t & 7) ^ (srow & 7)) * 16;
  const char* gA[4]; const char* gB[4];
#pragma unroll
  for (int q = 0; q < 4; ++q) {
    const int rowq = q * 32 + srow;
    long ga = m0 + rowq;
    if (ag) ga = (ga < Mg) ? (long)ag[(size_t)b * ag_stride + ga] : 0;
    gA[q] = (const char*)(Ab + ga * lda) + scol;
    long gb = n0 + rowq;
    if (bg) gb = (gb < Ng) ? (long)bg[(size_t)b * bg_stride + gb] : 0;
    gB[q] = (const char*)(Bb_ + gb * ldb) + scol;
  }

  f32x4 acc[4][4] = {};
  const int fr = lane & 15, kg = lane >> 4, fx = lane & 7;

  for (int kk = 0; kk < Kd; kk += 64) {
    __syncthreads();
#pragma unroll
    for (int q = 0; q < 4; ++q) {
      gload_lds16(gA[q] + (size_t)kk * 2, smA + q * 4096 + t * 16);
      gload_lds16(gB[q] + (size_t)kk * 2, smB + q * 4096 + t * 16);
    }
    __syncthreads();
#pragma unroll
    for (int ks = 0; ks < 2; ++ks) {
      bf16x8 aF[4], bF[4];
      const int slotbase = kg | (ks << 2);
#pragma unroll
      for (int mi = 0; mi < 4; ++mi) {
        const int off = (wr * 64 + mi * 16 + fr) * 128 + ((slotbase ^ fx) << 4);
        aF[mi] = *(const bf16x8*)(smA + off);
      }
#pragma unroll
      for (int ni = 0; ni < 4; ++ni) {
        const int off = (wc * 64 + ni * 16 + fr) * 128 + ((slotbase ^ fx) << 4);
        bF[ni] = *(const bf16x8*)(smB + off);
      }
#pragma unroll
      for (int mi = 0; mi < 4; ++mi)
#pragma unroll
        for (int ni = 0; ni < 4; ++ni)
          acc[mi][ni] = __builtin_amdgcn_mfma_f32_16x16x32_bf16(
              aF[mi], bF[ni], acc[mi][ni], 0, 0, 0);
    }
  }

  const int crow0 = m0 + wr * 64 + (lane >> 4) * 4;
  const int ccol0 = n0 + wc * 64 + fr;
#pragma unroll
  for (int mi = 0; mi < 4; ++mi) {
#pragma unroll
    for (int r = 0; r < 4; ++r) {
      const int row = crow0 + mi * 16 + r;
      if (row >= Ms) continue;
#pragma unroll
      for (int ni = 0; ni < 4; ++ni) {
        const int col = ccol0 + ni * 16;
        if (col >= Ns) continue;
        C[(size_t)b * sC + (size_t)row * ldc + col] = cvt_out<TC>(acc[mi][ni][r]);
      }
    }
  }
}

// ---------------- pure-bf16 layer MFMA: P[sk] = A(rows,maybe gathered) @ B^T, split-K=4 ---
// DUAL=true: B = Bhi + Blo (2 MFMA, exact B). DUAL=false: single-B (round-2-validated class).
template<bool GATHER, bool DUAL>
__global__ __launch_bounds__(256, DUAL ? 3 : 4)
void mlayer2_k(const __hip_bfloat16* __restrict__ A, long lda, long sA,
               const __hip_bfloat16* __restrict__ Bhi,
               const __hip_bfloat16* __restrict__ Blo, long ldb, long sB,
               const int* __restrict__ ag, int ag_stride, int Mg,
               float* __restrict__ P, int Mpad, int Kchunk)
{
  __shared__ char smem[DUAL ? 49152 : 32768];
  char* smA   = smem;
  char* smBhi = smem + 16384;
  char* smBlo = smem + 32768;  // only used when DUAL
  const int t = threadIdx.x;
  const int b = blockIdx.z;
  const int sk = blockIdx.x;
  const int m0 = blockIdx.y * 128;
  const int k0 = sk * Kchunk;
  const int lane = t & 63, w = t >> 6;
  const int wr = w >> 1, wc = w & 1;

  const int srow = t >> 3;
  const int scol = ((t & 7) ^ (srow & 7)) * 16;
  const char* gA[4]; const char* gBhi[4]; const char* gBlo[4];
#pragma unroll
  for (int q = 0; q < 4; ++q) {
    const int rowq = q * 32 + srow;
    long ga = m0 + rowq;
    if (GATHER) ga = (ga < Mg) ? (long)ag[(size_t)b * ag_stride + ga] : 0;
    gA[q]   = (const char*)(A + (size_t)b * sA + ga * lda + k0) + scol;
    gBhi[q] = (const char*)(Bhi + (size_t)b * sB + (size_t)rowq * ldb + k0) + scol;
    if (DUAL) gBlo[q] = (const char*)(Blo + (size_t)b * sB + (size_t)rowq * ldb + k0) + scol;
  }

  f32x4 acc[4][4] = {};
  const int fr = lane & 15, kg = lane >> 4, fx = lane & 7;

  for (int ks = 0; ks < Kchunk; ks += 64) {
    __syncthreads();
#pragma unroll
    for (int q = 0; q < 4; ++q) {
      gload_lds16(gA[q]   + (size_t)ks * 2, smA   + q * 4096 + t * 16);
      gload_lds16(gBhi[q] + (size_t)ks * 2, smBhi + q * 4096 + t * 16);
      if (DUAL) gload_lds16(gBlo[q] + (size_t)ks * 2, smBlo + q * 4096 + t * 16);
    }
    __syncthreads();
#pragma unroll
    for (int ks2 = 0; ks2 < 2; ++ks2) {
      bf16x8 aF[4];
      const int slotbase = kg | (ks2 << 2);
#pragma unroll
      for (int mi = 0; mi < 4; ++mi) {
        const int off = (wr * 64 + mi * 16 + fr) * 128 + ((slotbase ^ fx) << 4);
        aF[mi] = *(const bf16x8*)(smA + off);
      }
#pragma unroll
      for (int ni = 0; ni < 4; ++ni) {
        const int off = (wc * 64 + ni * 16 + fr) * 128 + ((slotbase ^ fx) << 4);
        const bf16x8 bhi = *(const bf16x8*)(smBhi + off);
#pragma unroll
        for (int mi = 0; mi < 4; ++mi)
          acc[mi][ni] = __builtin_amdgcn_mfma_f32_16x16x32_bf16(aF[mi], bhi, acc[mi][ni], 0, 0, 0);
        if (DUAL) {
          const bf16x8 blo = *(const bf16x8*)(smBlo + off);
#pragma unroll
          for (int mi = 0; mi < 4; ++mi)
            acc[mi][ni] = __builtin_amdgcn_mfma_f32_16x16x32_bf16(aF[mi], blo, acc[mi][ni], 0, 0, 0);
        }
      }
    }
  }

  float* Pp = P + ((size_t)sk * Bb + b) * Mpad * 128;
  const int crow0 = m0 + wr * 64 + (lane >> 4) * 4;
  const int ccol0 = wc * 64 + fr;
#pragma unroll
  for (int mi = 0; mi < 4; ++mi)
#pragma unroll
    for (int r = 0; r < 4; ++r) {
      const int row = crow0 + mi * 16 + r;
#pragma unroll
      for (int ni = 0; ni < 4; ++ni)
        Pp[(size_t)row * 128 + ccol0 + ni * 16] = acc[mi][ni][r];
    }
}

// ---------------- split-K reduce (sk = 4) ----------------
template<bool MASKED>
__global__ __launch_bounds__(256)
void red_layer_k(const float* __restrict__ P, const float* __restrict__ bias,
                 const float* __restrict__ mask, float* __restrict__ out)
{
  const size_t o = ((size_t)blockIdx.x * 256 + threadIdx.x) * 4;
  const size_t stride = (size_t)Bb * Nn * Hh;
  float4 s = {0.f, 0.f, 0.f, 0.f};
#pragma unroll
  for (int sk = 0; sk < 4; ++sk) {
    const float4 v = *(const float4*)(P + sk * stride + o);
    s.x += v.x; s.y += v.y; s.z += v.z; s.w += v.w;
  }
  const int h = (int)(o & 127);
  const float4 bi = *(const float4*)(bias + h);
  s.x = fmaxf(s.x + bi.x, 0.f);
  s.y = fmaxf(s.y + bi.y, 0.f);
  s.z = fmaxf(s.z + bi.z, 0.f);
  s.w = fmaxf(s.w + bi.w, 0.f);
  if (MASKED) {
    const int n = (int)((o >> 7) & (Nn - 1));
    const int b = (int)(o >> 18);
    const float m = mask[b * Nn + n];
    s.x *= m; s.y *= m; s.z *= m; s.w *= m;
  }
  *(float4*)(out + o) = s;
}

__global__ __launch_bounds__(128)
void red_hout_k(const float* __restrict__ P, float* __restrict__ Hout)
{
  const int k = blockIdx.x, b = blockIdx.y, h = threadIdx.x;
  const size_t stride = (size_t)Bb * KpPad * Hh;
  float s = 0.f;
#pragma unroll
  for (int sk = 0; sk < 4; ++sk)
    s += P[sk * stride + ((size_t)b * KpPad + k) * 128 + h];
  Hout[((size_t)b * Kp + k) * 128 + h] = s;
}

// ---------------- fp32 @W GEMM, K split in 2 ----------------
__global__ __launch_bounds__(256)
void wgemm_k(const float* __restrict__ A, long sA,
             const float* __restrict__ W,
             float* __restrict__ Cp)
{
  __shared__ float As[16][128];
  __shared__ float Bs[16][128];
  const int tid = threadIdx.x;
  const int p = blockIdx.x;
  const int b = blockIdx.z;
  const int m0 = blockIdx.y * 128;
  const int k0 = p * 64;
  const int ty = tid >> 4, tx = tid & 15;

  const float* Ab = A + (size_t)b * sA;

  float acc[8][8];
#pragma unroll
  for (int r = 0; r < 8; ++r)
#pragma unroll
    for (int c = 0; c < 8; ++c) acc[r][c] = 0.f;

  const int ai = tid >> 1;
  const int ak0 = (tid & 1) * 8;

  for (int kk0 = k0; kk0 < k0 + 64; kk0 += 16) {
    float av[8];
    load8<float>(Ab + (size_t)(m0 + ai) * Hh + kk0 + ak0, av);
    float bv[8];
    const int bk_row = tid >> 4, bj0 = (tid & 15) * 8;
    load8<float>(W + (size_t)(kk0 + bk_row) * Hh + bj0, bv);

    __syncthreads();
#pragma unroll
    for (int e = 0; e < 8; ++e) Bs[bk_row][bj0 + e] = bv[e];
#pragma unroll
    for (int e = 0; e < 8; ++e) As[ak0 + e][ai] = av[e];
    __syncthreads();

#pragma unroll
    for (int k = 0; k < 16; ++k) {
      const float4 a0 = *reinterpret_cast<const float4*>(&As[k][4 * ty]);
      const float4 a1 = *reinterpret_cast<const float4*>(&As[k][64 + 4 * ty]);
      const float4 b0 = *reinterpret_cast<const float4*>(&Bs[k][4 * tx]);
      const float4 b1 = *reinterpret_cast<const float4*>(&Bs[k][64 + 4 * tx]);
      const float ar[8] = {a0.x, a0.y, a0.z, a0.w, a1.x, a1.y, a1.z, a1.w};
      const float br[8] = {b0.x, b0.y, b0.z, b0.w, b1.x, b1.y, b1.z, b1.w};
#pragma unroll
      for (int r = 0; r < 8; ++r)
#pragma unroll
        for (int c = 0; c < 8; ++c)
          acc[r][c] = fmaf(ar[r], br[c], acc[r][c]);
    }
  }

  float* Cb = Cp + (size_t)p * Bb * Nn * Hh + (size_t)b * sA;
#pragma unroll
  for (int r = 0; r < 8; ++r) {
    const int gi = m0 + ((r < 4) ? (4 * ty + r) : (64 + 4 * ty + r - 4));
#pragma unroll
    for (int c = 0; c < 8; ++c) {
      const int gj = (c < 4) ? (4 * tx + c) : (64 + 4 * tx + c - 4);
      Cb[(size_t)gi * Hh + gj] = acc[r][c];
    }
  }
}

// ---------------- converters ----------------

__global__ __launch_bounds__(256)
void prep_k(const float* __restrict__ adj, const float* __restrict__ invc,
            __hip_bfloat16* __restrict__ S, __hip_bfloat16* __restrict__ At,
            float* __restrict__ pa)
{
  __shared__ float tile[32][36];
  const int b = blockIdx.z;
  const long j0 = (long)blockIdx.x * 32;
  const long ibase = (long)blockIdx.y * 64;
  const int r = threadIdx.x >> 3, c4 = (threadIdx.x & 7) * 4;
  const float4 ic = *(const float4*)(invc + (size_t)b * Nn + j0 + c4);
  float cs = 0.f;
#pragma unroll
  for (int st = 0; st < 2; ++st) {
    const long i0 = ibase + st * 32;
    const float4 v = *(const float4*)(adj + ((size_t)b * Nn + (i0 + r)) * Nn + j0 + c4);
    ushort4 sv;
    sv.x = f2bfbits(v.x * ic.x);
    sv.y = f2bfbits(v.y * ic.y);
    sv.z = f2bfbits(v.z * ic.z);
    sv.w = f2bfbits(v.w * ic.w);
    *(ushort4*)((unsigned short*)S + ((size_t)b * Nn + (i0 + r)) * Nn + j0 + c4) = sv;
    tile[r][c4 + 0] = v.x;
    tile[r][c4 + 1] = v.y;
    tile[r][c4 + 2] = v.z;
    tile[r][c4 + 3] = v.w;
    __syncthreads();
    ushort4 tv;
    tv.x = f2bfbits(tile[c4 + 0][r]);
    tv.y = f2bfbits(tile[c4 + 1][r]);
    tv.z = f2bfbits(tile[c4 + 2][r]);
    tv.w = f2bfbits(tile[c4 + 3][r]);
    *(ushort4*)((unsigned short*)At + ((size_t)b * Nn + (j0 + r)) * Nn + i0 + c4) = tv;
    if (threadIdx.x < 32) {
      float a = 0.f;
#pragma unroll
      for (int rr = 0; rr < 32; ++rr) a += tile[rr][threadIdx.x];
      cs += a;
    }
    __syncthreads();
  }
  if (threadIdx.x < 32)
    pa[(((size_t)b * 32 + blockIdx.y) << 11) + j0 + threadIdx.x] = cs;
}

// dst[b,j,i] = bf16((p0+p1)[b,i,j] * scale[b,i]) (+ lo residual if SPLIT)
template<bool SPLIT>
__global__ __launch_bounds__(256)
void tconv2_k(const float* __restrict__ p0, const float* __restrict__ p1,
              long ld_src, long s_src,
              const float* __restrict__ scale, long scale_stride,
              __hip_bfloat16* __restrict__ dst, __hip_bfloat16* __restrict__ dlo,
              long ld_dst, long s_dst)
{
  __shared__ float tile[32][36];
  const int b = blockIdx.z;
  const long i0 = (long)blockIdx.y * 32, j0 = (long)blockIdx.x * 32;
  const int r = threadIdx.x >> 3, c4 = (threadIdx.x & 7) * 4;
  const size_t soff = (size_t)b * s_src + (i0 + r) * ld_src + j0 + c4;
  float4 v = *(const float4*)(p0 + soff);
  if (p1) {
    const float4 u = *(const float4*)(p1 + soff);
    v.x += u.x; v.y += u.y; v.z += u.z; v.w += u.w;
  }
  const float sc = scale[(size_t)b * scale_stride + i0 + r];
  tile[r][c4 + 0] = v.x * sc;
  tile[r][c4 + 1] = v.y * sc;
  tile[r][c4 + 2] = v.z * sc;
  tile[r][c4 + 3] = v.w * sc;
  __syncthreads();
  float t0 = tile[c4 + 0][r], t1 = tile[c4 + 1][r], t2 = tile[c4 + 2][r], t3 = tile[c4 + 3][r];
  ushort4 hi;
  hi.x = f2bfbits(t0); hi.y = f2bfbits(t1); hi.z = f2bfbits(t2); hi.w = f2bfbits(t3);
  const size_t doff = (size_t)b * s_dst + (j0 + r) * ld_dst + i0 + c4;
  *(ushort4*)((unsigned short*)dst + doff) = hi;
  if (SPLIT) {
    ushort4 lo;
    lo.x = f2bfbits(t0 - bf2f(hi.x));
    lo.y = f2bfbits(t1 - bf2f(hi.y));
    lo.z = f2bfbits(t2 - bf2f(hi.z));
    lo.w = f2bfbits(t3 - bf2f(hi.w));
    *(ushort4*)((unsigned short*)dlo + doff) = lo;
  }
}

// ---------------- parallel reductions ----------------

__global__ __launch_bounds__(256)
void colsum_c_part_k(const float* __restrict__ adj, const int* __restrict__ top,
                     float* __restrict__ pc)
{
  __shared__ int rows[180];
  const int b = blockIdx.z, ch = blockIdx.y;
  const int n = blockIdx.x * 256 + threadIdx.x;
  const int k0 = ch * 180;
  const int cnt = min(Kp - k0, 180);
  for (int k = threadIdx.x; k < cnt; k += 256) rows[k] = top[b * Kp + k0 + k];
  __syncthreads();
  const float* ab = adj + (size_t)b * Nn * Nn;
  float a0 = 0.f, a1 = 0.f, a2 = 0.f, a3 = 0.f;
  int k = 0;
  for (; k + 4 <= cnt; k += 4) {
    a0 += ab[(size_t)rows[k + 0] * Nn + n];
    a1 += ab[(size_t)rows[k + 1] * Nn + n];
    a2 += ab[(size_t)rows[k + 2] * Nn + n];
    a3 += ab[(size_t)rows[k + 3] * Nn + n];
  }
  for (; k < cnt; ++k) a0 += ab[(size_t)rows[k] * Nn + n];
  pc[(((size_t)b * 8 + ch) << 11) + n] = (a0 + a1) + (a2 + a3);
}

__global__ __launch_bounds__(256)
void invc_fin_k(const float* __restrict__ pc, float* __restrict__ invc,
                float* __restrict__ cvec)
{
  const int i = blockIdx.x * 256 + threadIdx.x;
  const int b = i >> 11, n = i & (Nn - 1);
  float s = 0.f;
#pragma unroll
  for (int ch = 0; ch < 8; ++ch) s += pc[(((size_t)b * 8 + ch) << 11) + n];
  const float c = s + kEps;
  cvec[i] = c;
  invc[i] = 1.f / c;
}

__global__ __launch_bounds__(256)
void csum_fin_k(const float* __restrict__ pa, float* __restrict__ csum)
{
  const int i = blockIdx.x * 256 + threadIdx.x;
  const int b = i >> 11, m = i & (Nn - 1);
  float s = 0.f;
#pragma unroll
  for (int ch = 0; ch < 32; ++ch) s += pa[(((size_t)b * 32 + ch) << 11) + m];
  csum[i] = s;
}

// denom from bf16 S: denom[n] = sum_m S[n,m]*(cvec*atte)[m]; diag = S[n,n]*cvec[n]
__global__ __launch_bounds__(256)
void denom2_k(const __hip_bfloat16* __restrict__ S, const float* __restrict__ ca,
              const float* __restrict__ cvec,
              float* __restrict__ denom, float* __restrict__ diag)
{
  const int b = blockIdx.y;
  const int w = threadIdx.x >> 6, lane = threadIdx.x & 63;
  const int n = blockIdx.x * 4 + w;
  const unsigned short* srow = (const unsigned short*)S + ((size_t)b * Nn + n) * Nn;
  const float* cap = ca + (size_t)b * Nn;
  float acc = 0.f;
#pragma unroll
  for (int j = 0; j < 4; ++j) {
    const int o = j * 512 + lane * 8;
    const uint4 u = *(const uint4*)(srow + o);
    const float4 c0 = *(const float4*)(cap + o);
    const float4 c1 = *(const float4*)(cap + o + 4);
    acc += bf2f(u.x & 0xffffu) * c0.x + bf2f(u.x >> 16) * c0.y
         + bf2f(u.y & 0xffffu) * c0.z + bf2f(u.y >> 16) * c0.w
         + bf2f(u.z & 0xffffu) * c1.x + bf2f(u.z >> 16) * c1.y
         + bf2f(u.w & 0xffffu) * c1.z + bf2f(u.w >> 16) * c1.w;
  }
#pragma unroll
  for (int o = 32; o; o >>= 1) acc += __shfl_down(acc, o, 64);
  if (lane == 0) {
    denom[(size_t)b * Nn + n] = acc;
    diag[(size_t)b * Nn + n] = bf2f(srow[n]) * cvec[(size_t)b * Nn + n];
  }
}

__global__ __launch_bounds__(128)
void readout_part_k(const float* __restrict__ hid, const float* __restrict__ mask,
                    float* __restrict__ rp)
{
  const int b = blockIdx.y, ch = blockIdx.x, h = threadIdx.x;
  const float* hp = hid + ((size_t)b * Nn + ch * 128) * Hh;
  const float* mp = mask + (size_t)b * Nn + ch * 128;
  float acc = 0.f;
#pragma unroll 1
  for (int r = 0; r < 128; ++r) acc += mp[r] * hp[(size_t)r * Hh + h];
  rp[(((size_t)b * 16 + ch) << 7) + h] = acc;
}

__global__ __launch_bounds__(128)
void readout_fin_k(const float* __restrict__ rp, const float* __restrict__ mask,
                   float* __restrict__ out)
{
  __shared__ float sm[128];
  const int b = blockIdx.x, h = threadIdx.x;
  float acc = 0.f;
#pragma unroll
  for (int ch = 0; ch < 16; ++ch) acc += rp[(((size_t)b * 16 + ch) << 7) + h];
  float ms = 0.f;
#pragma unroll
  for (int j = 0; j < 16; ++j) ms += mask[(size_t)b * Nn + h * 16 + j];
  sm[h] = ms;
  __syncthreads();
  for (int o = 64; o; o >>= 1) {
    if (h < o) sm[h] += sm[h + o];
    __syncthreads();
  }
  out[(size_t)b * Hh + h] = acc / sm[0];
}

// ---------------- attention scalars ----------------

__global__ __launch_bounds__(256)
void scores_k(const float* __restrict__ hidden, const float* __restrict__ wb,
              const float* __restrict__ mask, float* __restrict__ s)
{
  const int wid = threadIdx.x >> 6, lane = threadIdx.x & 63;
  const int row = blockIdx.x * 4 + wid;
  const float* hp = hidden + (size_t)row * Hh;
  float acc = hp[lane] * wb[lane] + hp[64 + lane] * wb[64 + lane];
#pragma unroll
  for (int o = 32; o; o >>= 1) acc += __shfl_down(acc, o, 64);
  if (lane == 0) s[row] = acc + (mask[row] - 1.f) * kBig;
}

__global__ __launch_bounds__(256)
void rowmax_k(const float* __restrict__ s, float* __restrict__ rmax)
{
  __shared__ float red[256];
  const int b = blockIdx.x;
  float m = -3.4e38f;
  for (int n = threadIdx.x; n < Nn; n += 256) m = fmaxf(m, s[b * Nn + n]);
  red[threadIdx.x] = m;
  __syncthreads();
  for (int o = 128; o; o >>= 1) {
    if (threadIdx.x < o) red[threadIdx.x] = fmaxf(red[threadIdx.x], red[threadIdx.x + o]);
    __syncthreads();
  }
  if (threadIdx.x == 0) rmax[b] = red[0];
}

__global__ __launch_bounds__(256)
void attexp_k(const float* __restrict__ s, const float* __restrict__ rmax,
              const float* __restrict__ tau, const float* __restrict__ cvec,
              float* __restrict__ atte, float* __restrict__ ca)
{
  const int i = blockIdx.x * 256 + threadIdx.x;
  const int b = i >> 11;
  const float e = expf((s[i] - rmax[b]) * fabsf(*tau));
  atte[i] = e;
  ca[i] = e * cvec[i];
}

// att = atte*diag/(denom+EPS)*csum*mask
__global__ __launch_bounds__(256)
void att_final_k(const float* __restrict__ atte, const float* __restrict__ diag,
                 const float* __restrict__ denom, const float* __restrict__ colsum,
                 const float* __restrict__ mask, float* __restrict__ att)
{
  const int i = blockIdx.x * 256 + threadIdx.x;
  att[i] = atte[i] * diag[i] / (denom[i] + kEps) * colsum[i] * mask[i];
}

__global__ __launch_bounds__(256)
void ones_k(float* __restrict__ p, int n)
{
  const int i = blockIdx.x * 256 + threadIdx.x;
  if (i < n) p[i] = 1.f;
}

}  // namespace

extern "C" void kernel_launch(void* const* d_in, const int* in_sizes, int n_in,
                              void* d_out, int out_size, void* d_ws, size_t ws_size,
                              hipStream_t stream) {
  const float* X    = (const float*)d_in[0];
  const float* adj  = (const float*)d_in[1];
  const float* mask = (const float*)d_in[2];
  const float* W1   = (const float*)d_in[3];
  const float* b1   = (const float*)d_in[4];
  const float* W2   = (const float*)d_in[5];
  const float* b2   = (const float*)d_in[6];
  const float* wb   = (const float*)d_in[7];
  const float* tau  = (const float*)d_in[8];
  const int*   top  = (const int*)d_in[9];
  float* out = (float*)d_out;

  // ws layout (float offsets)
  float* ws    = (float*)d_ws;
  float* h1hid = ws;                   // [B,N,H] f32
  float* Btf   = ws + 2097152;         // Bt hi/lo bf16 pair region (8MB)
  float* invc  = ws + 4194304;         // [B,N]
  float* cvec  = ws + 4210688;
  float* s     = ws + 4227072;
  float* atte  = ws + 4243456;
  float* den   = ws + 4259840;
  float* diag  = ws + 4276224;
  float* csum  = ws + 4292608;
  float* att   = ws + 4308992;
  float* ca    = ws + 4325376;
  float* rmax  = ws + 4341760;         // 256
  float* pc    = ws + 4342016;         // [B][8][N]   131072
  float* pa    = ws + 4473088;         // [B][32][N]  524288
  float* rp    = ws + 4997376;         // [B][16][H]  16384
  __hip_bfloat16* S   = (__hip_bfloat16*)(ws + 5013760);   // [B,N,N] bf16, 67.1MB
  __hip_bfloat16* At  = S + (size_t)Bb * Nn * Nn;          // 67.1MB: At bf16, later P f32
  float*          P   = (float*)At;                        // [4][B][Mpad][128] f32
  __hip_bfloat16* T   = At + (size_t)Bb * Nn * Nn;         // [B,1536,N] bf16, later Tpart f32
  float*          Tpart = (float*)T;                       // [2][B,2048,128] f32 = 16MB
  if (ws_size < 204604416u) return;    // ~204.6 MB scratch

  __hip_bfloat16* Bthi = (__hip_bfloat16*)Btf;             // [B,128,2048] bf16
  __hip_bfloat16* Btlo = Bthi + (size_t)Bb * Hh * Nn;

  float* Hout    = out + 1024;
  float* newadj  = out + 1469440;
  float* newmask = out + 17920288;

  const long sAdj = (long)Nn * Nn;
  const long sNH  = (long)Nn * Hh;
  const long sHN  = (long)Hh * Nn;
  const long sT   = (long)KpPad * Nn;
  const long sNew = (long)Kp * Kp;

  // 1. assign-column normalizer (split-K parallel) -> invc, cvec
  colsum_c_part_k<<<dim3(Nn / 256, 8, Bb), 256, 0, stream>>>(adj, top, pc);
  invc_fin_k<<<dim3(Bb * Nn / 256), 256, 0, stream>>>(pc, invc, cvec);

  // 2. fused prep: one adj read -> S = adj*invc[col], At = adj^T, pa = colsum partials
  prep_k<<<dim3(Nn / 32, Nn / 64, Bb), 256, 0, stream>>>(adj, invc, S, At, pa);
  csum_fin_k<<<dim3(Bb * Nn / 256), 256, 0, stream>>>(pa, csum);

  // 3. T = S(gathered) @ At^T ; new_adj = T @ S(gathered)^T  (XCD-swizzled, 16x16 MFMA)
  mgemm_k<__hip_bfloat16><<<dim3(Nn / 128, KpPad / 128, Bb), 256, 0, stream>>>(
      S, Nn, sAdj, At, Nn, sAdj, top, Kp, Kp, nullptr, 0, 0,
      T, Nn, sT, KpPad, Nn, Nn);
  mgemm_k<float><<<dim3(KpPad / 128, KpPad / 128, Bb), 256, 0, stream>>>(
      T, Nn, sT, S, Nn, sAdj, nullptr, 0, 0, top, Kp, Kp,
      newadj, Kp, sNew, Kp, Kp, Nn);
  // At region dead -> P ; T region dead -> Tpart

  // 4. GCN layer 1: XW1 = X@W1 (K-split-2); h1 = relu(S@(cvec.*XW1)+b1)
  //    single-B (round-2-validated error class: both GEMM operands single-rounded bf16)
  wgemm_k<<<dim3(2, Nn / 128, Bb), 256, 0, stream>>>(X, sNH, W1, Tpart);
  tconv2_k<false><<<dim3(Hh / 32, Nn / 32, Bb), 256, 0, stream>>>(
      Tpart, Tpart + (size_t)Bb * Nn * Hh, Hh, sNH, cvec, Nn, Bthi, Btlo, Nn, sHN);
  mlayer2_k<false, false><<<dim3(4, Nn / 128, Bb), 256, 0, stream>>>(
      S, Nn, sAdj, Bthi, Btlo, Nn, sHN, nullptr, 0, 0, P, Nn, Nn / 4);
  red_layer_k<false><<<dim3(2048), 256, 0, stream>>>(P, b1, nullptr, h1hid);

  // 5. GCN layer 2 (keep exact-B: feeds scores/exp most directly)
  wgemm_k<<<dim3(2, Nn / 128, Bb), 256, 0, stream>>>(h1hid, sNH, W2, Tpart);
  tconv2_k<true><<<dim3(Hh / 32, Nn / 32, Bb), 256, 0, stream>>>(
      Tpart, Tpart + (size_t)Bb * Nn * Hh, Hh, sNH, cvec, Nn, Bthi, Btlo, Nn, sHN);
  mlayer2_k<false, true><<<dim3(4, Nn / 128, Bb), 256, 0, stream>>>(
      S, Nn, sAdj, Bthi, Btlo, Nn, sHN, nullptr, 0, 0, P, Nn, Nn / 4);
  red_layer_k<true><<<dim3(2048), 256, 0, stream>>>(P, b2, mask, h1hid);

  // 6. attention scalars (denom/diag from bf16 S, half traffic)
  scores_k<<<dim3(Bb * Nn / 4), 256, 0, stream>>>(h1hid, wb, mask, s);
  rowmax_k<<<dim3(Bb), 256, 0, stream>>>(s, rmax);
  attexp_k<<<dim3(Bb * Nn / 256), 256, 0, stream>>>(s, rmax, tau, cvec, atte, ca);
  denom2_k<<<dim3(Nn / 4, Bb), 256, 0, stream>>>(S, ca, cvec, den, diag);
  att_final_k<<<dim3(Bb * Nn / 256), 256, 0, stream>>>(atte, diag, den, csum, mask, att);

  // 7. H_out = gather(S) @ (att .* hid)   (single-B: linear path, bf16-A class error)
  tconv2_k<false><<<dim3(Hh / 32, Nn / 32, Bb), 256, 0, stream>>>(
      h1hid, nullptr, Hh, sNH, att, Nn, Bthi, Btlo, Nn, sHN);
  mlayer2_k<true, false><<<dim3(4, KpPad / 128, Bb), 256, 0, stream>>>(
      S, Nn, sAdj, Bthi, Btlo, Nn, sHN, top, Kp, Kp, P, KpPad, Nn / 4);
  red_hout_k<<<dim3(Kp, Bb), 128, 0, stream>>>(P, Hout);

  // 8. readout + new_mask
  readout_part_k<<<dim3(16, Bb), 128, 0, stream>>>(h1hid, mask, rp);
  readout_fin_k<<<dim3(Bb), 128, 0, stream>>>(rp, mask, out);
  ones_k<<<dim3((Bb * Kp + 255) / 256), 256, 0, stream>>>(newmask, Bb * Kp);
}